// Round 1
// baseline (5049.226 us; speedup 1.0000x reference)
//
#include <hip/hip_runtime.h>
#include <cstdint>

#define EPSV 1e-5f

// ---------------------------------------------------------------- init ----
__global__ __launch_bounds__(256) void k_init(float* __restrict__ deg,
                                              float* __restrict__ pool, int N) {
    const int i = blockIdx.x * 256 + threadIdx.x;
    if (i < N) deg[i] = 1.0f;              // self-loop weight
    if (i < 64 * 64 + 64) pool[i] = 0.0f;  // pooled sums + counts
}

__global__ __launch_bounds__(256) void k_degacc(const int* __restrict__ ei,
                                                const float* __restrict__ ew,
                                                float* __restrict__ deg, int E) {
    const int e = blockIdx.x * 256 + threadIdx.x;
    if (e < E) unsafeAtomicAdd(&deg[ei[E + e]], ew[e]);
}

__global__ __launch_bounds__(256) void k_dinv(float* __restrict__ deg, int N) {
    const int i = blockIdx.x * 256 + threadIdx.x;
    if (i < N) {
        const float d = deg[i];
        deg[i] = d > 0.f ? rsqrtf(fmaxf(d, EPSV)) : 0.f;
    }
}

// ---------------------------------------------------------------- GEMM ----
// H[N][NOUT] = X[N][K] @ W[K][NOUT]; Binit = H * dinv^2 (self-loop term).
// 32 nodes/block, X tile staged in LDS, 8 nodes per wave, NOUT/64 cols/lane.
template <int K, int NOUT>
__global__ __launch_bounds__(256) void k_gemm(const float* __restrict__ X,
                                              const float* __restrict__ W,
                                              const float* __restrict__ dinv,
                                              float* __restrict__ H,
                                              float* __restrict__ Binit, int N) {
    constexpr int NT = 32;
    constexpr int CPL = NOUT / 64;
    __shared__ float xs[NT * K];
    const int tid = threadIdx.x;
    const long base = (long)blockIdx.x * NT;

    // stage X tile (coalesced float4)
    const float4* Xg = reinterpret_cast<const float4*>(X + base * K);
    float4* xs4 = reinterpret_cast<float4*>(xs);
    constexpr int TOT4 = NT * K / 4;
    const long max4 = ((long)N * K) / 4 - base * (K / 4);
#pragma unroll
    for (int i = 0; i < TOT4 / 256; ++i) {
        const int idx = tid + i * 256;
        if (idx < max4) xs4[idx] = Xg[idx];
    }
    __syncthreads();

    const int wave = tid >> 6, lane = tid & 63;
    float acc[8][CPL];
#pragma unroll
    for (int n = 0; n < 8; ++n)
#pragma unroll
        for (int c = 0; c < CPL; ++c) acc[n][c] = 0.f;

    const float* xw = xs + wave * 8 * K;
    for (int k4 = 0; k4 < K / 4; ++k4) {
        float wv[4][CPL];
#pragma unroll
        for (int kk = 0; kk < 4; ++kk)
#pragma unroll
            for (int c = 0; c < CPL; ++c)
                wv[kk][c] = W[(k4 * 4 + kk) * NOUT + c * 64 + lane];
#pragma unroll
        for (int n = 0; n < 8; ++n) {
            const float4 xv = *reinterpret_cast<const float4*>(xw + n * K + k4 * 4);
#pragma unroll
            for (int c = 0; c < CPL; ++c) {
                acc[n][c] += xv.x * wv[0][c];
                acc[n][c] += xv.y * wv[1][c];
                acc[n][c] += xv.z * wv[2][c];
                acc[n][c] += xv.w * wv[3][c];
            }
        }
    }

#pragma unroll
    for (int n = 0; n < 8; ++n) {
        const long node = base + wave * 8 + n;
        if (node < N) {
            const float d = dinv[node];
            const float d2 = d * d;
#pragma unroll
            for (int c = 0; c < CPL; ++c) {
                const float v = acc[n][c];
                H[node * NOUT + c * 64 + lane] = v;
                Binit[node * NOUT + c * 64 + lane] = v * d2;
            }
        }
    }
}

// -------------------------------------------------------- edge scatter ----
// Out[col] += H[row] * (dinv[row]*w*dinv[col]);  D/4 lanes per edge, float4.
template <int D>
__global__ __launch_bounds__(256) void k_agg(const float* __restrict__ H,
                                             const int* __restrict__ ei,
                                             const float* __restrict__ ew,
                                             const float* __restrict__ dinv,
                                             float* __restrict__ Out, int E) {
    constexpr int LPE = D / 4;
    const long tid = (long)blockIdx.x * 256 + threadIdx.x;
    const long e = tid / LPE;
    const int sl = (int)(tid % LPE);
    if (e >= E) return;
    const int r = ei[e];
    const int c = ei[E + e];
    const float nrm = dinv[r] * ew[e] * dinv[c];
    const float4 v = *reinterpret_cast<const float4*>(H + (long)r * D + sl * 4);
    float* o = Out + (long)c * D + sl * 4;
    unsafeAtomicAdd(o + 0, v.x * nrm);
    unsafeAtomicAdd(o + 1, v.y * nrm);
    unsafeAtomicAdd(o + 2, v.z * nrm);
    unsafeAtomicAdd(o + 3, v.w * nrm);
}

// ------------------------------------------- bias + ReLU + LayerNorm ------
template <int D>
__global__ __launch_bounds__(256) void k_post(float* __restrict__ IO,
                                              const float* __restrict__ bias,
                                              const float* __restrict__ gm,
                                              const float* __restrict__ bt, int N) {
    constexpr int VPL = D / 64;
    const long wv = ((long)blockIdx.x * 256 + threadIdx.x) >> 6;
    const int lane = threadIdx.x & 63;
    if (wv >= N) return;
    float* p = IO + wv * D;
    float t[VPL];
    float s1 = 0.f, s2 = 0.f;
#pragma unroll
    for (int v = 0; v < VPL; ++v) {
        float u = p[v * 64 + lane] + bias[v * 64 + lane];
        u = fmaxf(u, 0.f);
        t[v] = u;
        s1 += u;
        s2 += u * u;
    }
#pragma unroll
    for (int off = 32; off >= 1; off >>= 1) {
        s1 += __shfl_xor(s1, off);
        s2 += __shfl_xor(s2, off);
    }
    const float mu = s1 / (float)D;
    const float var = s2 / (float)D - mu * mu;
    const float rs = rsqrtf(var + EPSV);
#pragma unroll
    for (int v = 0; v < VPL; ++v)
        p[v * 64 + lane] = (t[v] - mu) * rs * gm[v * 64 + lane] + bt[v * 64 + lane];
}

// ---------------------------------------------------------------- pool ----
__global__ __launch_bounds__(256) void k_pool(const float* __restrict__ Hf,
                                              const int* __restrict__ batch,
                                              float* __restrict__ pool, int N) {
    const long wv = ((long)blockIdx.x * 256 + threadIdx.x) >> 6;
    const int lane = threadIdx.x & 63;
    if (wv >= N) return;
    const int b = batch[wv];
    unsafeAtomicAdd(&pool[b * 64 + lane], Hf[wv * 64 + lane]);
    if (lane == 0) unsafeAtomicAdd(&pool[64 * 64 + b], 1.0f);
}

__global__ __launch_bounds__(256) void k_final(const float* __restrict__ pool,
                                               float* __restrict__ out) {
    const int i = blockIdx.x * 256 + threadIdx.x;
    if (i < 4096) {
        const int g = i >> 6;
        const float cnt = fmaxf(pool[64 * 64 + g], 1.0f);
        const float v = pool[i] / cnt;
        out[i] = 1.f / (1.f + expf(-v));
    }
}

// -------------------------------------------------------------- launch ----
extern "C" void kernel_launch(void* const* d_in, const int* in_sizes, int n_in,
                              void* d_out, int out_size, void* d_ws, size_t ws_size,
                              hipStream_t stream) {
    const float* x   = (const float*)d_in[0];
    const int*   ei  = (const int*)d_in[1];
    const float* ew  = (const float*)d_in[2];
    const int*   bat = (const int*)d_in[3];
    const float* W1  = (const float*)d_in[4];
    const float* b1  = (const float*)d_in[5];
    const float* g1  = (const float*)d_in[6];
    const float* bt1 = (const float*)d_in[7];
    const float* W2  = (const float*)d_in[8];
    const float* b2  = (const float*)d_in[9];
    const float* g2  = (const float*)d_in[10];
    const float* bt2 = (const float*)d_in[11];
    const int N = in_sizes[3];
    const int E = in_sizes[2];

    float* ws   = (float*)d_ws;
    float* A    = ws;                   // [N][128] h1; then h2 packed [N][64]
    float* B    = A + (long)N * 128;    // [N][128] out1 -> x2
    float* C    = B + (long)N * 128;    // [N][64]  out2 -> final node feats
    float* deg  = C + (long)N * 64;     // [N] deg -> dinv (in place)
    float* pool = deg + N;              // [64*64 + 64]

    const int nbN = (N + 255) / 256;
    k_init<<<nbN, 256, 0, stream>>>(deg, pool, N);
    k_degacc<<<(E + 255) / 256, 256, 0, stream>>>(ei, ew, deg, E);
    k_dinv<<<nbN, 256, 0, stream>>>(deg, N);

    // layer 1: GCNConv(256->128) + ReLU + LN
    k_gemm<256, 128><<<(N + 31) / 32, 256, 0, stream>>>(x, W1, deg, A, B, N);
    k_agg<128><<<(int)(((long)E * 32 + 255) / 256), 256, 0, stream>>>(A, ei, ew, deg, B, E);
    k_post<128><<<(int)(((long)N * 64 + 255) / 256), 256, 0, stream>>>(B, b1, g1, bt1, N);

    // layer 2: GCNConv(128->64) + ReLU + LN
    k_gemm<128, 64><<<(N + 31) / 32, 256, 0, stream>>>(B, W2, deg, A, C, N);
    k_agg<64><<<(int)(((long)E * 16 + 255) / 256), 256, 0, stream>>>(A, ei, ew, deg, C, E);
    k_post<64><<<(int)(((long)N * 64 + 255) / 256), 256, 0, stream>>>(C, b2, g2, bt2, N);

    // global mean pool + sigmoid
    k_pool<<<(int)(((long)N * 64 + 255) / 256), 256, 0, stream>>>(C, bat, pool, N);
    k_final<<<16, 256, 0, stream>>>(pool, (float*)d_out);
}

// Round 2
// 1703.543 us; speedup vs baseline: 2.9640x; 2.9640x over previous
//
#include <hip/hip_runtime.h>
#include <cstdint>

#define EPSV 1e-5f

// ---------------------------------------------------------------- init ----
__global__ __launch_bounds__(256) void k_init(float* __restrict__ deg,
                                              int* __restrict__ cnt,
                                              float* __restrict__ pool, int N) {
    const int i = blockIdx.x * 256 + threadIdx.x;
    if (i < N) { deg[i] = 1.0f; cnt[i] = 0; }  // self-loop weight, edge histogram
    if (i < 64 * 64 + 64) pool[i] = 0.0f;      // pooled sums + counts
}

__global__ __launch_bounds__(256) void k_degacc(const int* __restrict__ ei,
                                                const float* __restrict__ ew,
                                                float* __restrict__ deg,
                                                int* __restrict__ cnt, int E) {
    const int e = blockIdx.x * 256 + threadIdx.x;
    if (e < E) {
        const int c = ei[E + e];
        unsafeAtomicAdd(&deg[c], ew[e]);
        atomicAdd(&cnt[c], 1);
    }
}

__global__ __launch_bounds__(256) void k_dinv(float* __restrict__ deg, int N) {
    const int i = blockIdx.x * 256 + threadIdx.x;
    if (i < N) {
        const float d = deg[i];
        deg[i] = d > 0.f ? rsqrtf(fmaxf(d, EPSV)) : 0.f;
    }
}

// ------------------------------------------------------- prefix scan ------
// Single block of 256; exclusive scan of cnt[N] -> off[N], also copy to cursor.
__global__ __launch_bounds__(256) void k_scan(const int* __restrict__ cnt,
                                              int* __restrict__ off,
                                              int* __restrict__ cursor, int N) {
    __shared__ int carry;
    __shared__ int wsum[4];
    if (threadIdx.x == 0) carry = 0;
    __syncthreads();
    const int lane = threadIdx.x & 63, w = threadIdx.x >> 6;
    for (int base = 0; base < N; base += 256) {
        const int i = base + threadIdx.x;
        const int v = (i < N) ? cnt[i] : 0;
        int s = v;
#pragma unroll
        for (int o = 1; o < 64; o <<= 1) {
            const int t = __shfl_up(s, o);
            if (lane >= o) s += t;
        }
        if (lane == 63) wsum[w] = s;
        __syncthreads();
        int add = 0;
        for (int k = 0; k < w; ++k) add += wsum[k];
        int tot = wsum[0] + wsum[1] + wsum[2] + wsum[3];
        if (i < N) {
            const int excl = carry + s + add - v;
            off[i] = excl;
            cursor[i] = excl;
        }
        __syncthreads();
        if (threadIdx.x == 0) carry += tot;
        __syncthreads();
    }
}

// Scatter edges into CSR: ern[p] = (row_bits, norm)
__global__ __launch_bounds__(256) void k_fill(const int* __restrict__ ei,
                                              const float* __restrict__ ew,
                                              const float* __restrict__ dinv,
                                              int* __restrict__ cursor,
                                              float2* __restrict__ ern, int E) {
    const int e = blockIdx.x * 256 + threadIdx.x;
    if (e >= E) return;
    const int r = ei[e];
    const int c = ei[E + e];
    const int p = atomicAdd(&cursor[c], 1);
    ern[p] = make_float2(__int_as_float(r), dinv[r] * ew[e] * dinv[c]);
}

// ---------------------------------------------------------------- GEMM ----
// H[N][NOUT] = X[N][K] @ W[K][NOUT].
template <int K, int NOUT>
__global__ __launch_bounds__(256) void k_gemm(const float* __restrict__ X,
                                              const float* __restrict__ W,
                                              float* __restrict__ H, int N) {
    constexpr int NT = 32;
    constexpr int CPL = NOUT / 64;
    __shared__ float xs[NT * K];
    const int tid = threadIdx.x;
    const long base = (long)blockIdx.x * NT;

    const float4* Xg = reinterpret_cast<const float4*>(X + base * K);
    float4* xs4 = reinterpret_cast<float4*>(xs);
    constexpr int TOT4 = NT * K / 4;
    const long max4 = ((long)N * K) / 4 - base * (K / 4);
#pragma unroll
    for (int i = 0; i < TOT4 / 256; ++i) {
        const int idx = tid + i * 256;
        if (idx < max4) xs4[idx] = Xg[idx];
    }
    __syncthreads();

    const int wave = tid >> 6, lane = tid & 63;
    float acc[8][CPL];
#pragma unroll
    for (int n = 0; n < 8; ++n)
#pragma unroll
        for (int c = 0; c < CPL; ++c) acc[n][c] = 0.f;

    const float* xw = xs + wave * 8 * K;
    for (int k4 = 0; k4 < K / 4; ++k4) {
        float wv[4][CPL];
#pragma unroll
        for (int kk = 0; kk < 4; ++kk)
#pragma unroll
            for (int c = 0; c < CPL; ++c)
                wv[kk][c] = W[(k4 * 4 + kk) * NOUT + c * 64 + lane];
#pragma unroll
        for (int n = 0; n < 8; ++n) {
            const float4 xv = *reinterpret_cast<const float4*>(xw + n * K + k4 * 4);
#pragma unroll
            for (int c = 0; c < CPL; ++c) {
                acc[n][c] += xv.x * wv[0][c];
                acc[n][c] += xv.y * wv[1][c];
                acc[n][c] += xv.z * wv[2][c];
                acc[n][c] += xv.w * wv[3][c];
            }
        }
    }

#pragma unroll
    for (int n = 0; n < 8; ++n) {
        const long node = base + wave * 8 + n;
        if (node < N)
#pragma unroll
            for (int c = 0; c < CPL; ++c)
                H[node * NOUT + c * 64 + lane] = acc[n][c];
    }
}

// --------------------------------- gather + bias + ReLU + LayerNorm -------
// D=128: one wave per node, float2 per lane.
__global__ __launch_bounds__(256) void k_gat128(const float* __restrict__ H,
                                                const int* __restrict__ off,
                                                const int* __restrict__ cnt,
                                                const float2* __restrict__ ern,
                                                const float* __restrict__ dinv,
                                                const float* __restrict__ bias,
                                                const float* __restrict__ gm,
                                                const float* __restrict__ bt,
                                                float* __restrict__ Out, int N) {
    const long wv = ((long)blockIdx.x * 256 + threadIdx.x) >> 6;
    const int lane = threadIdx.x & 63;
    if (wv >= N) return;
    const int s = off[wv];
    const int n = cnt[wv];
    const float d = dinv[wv];
    const float2* Hp = reinterpret_cast<const float2*>(H);

    float2 h0 = Hp[wv * 64 + lane];
    float ax = h0.x * d * d, ay = h0.y * d * d;

    int e = 0;
    for (; e + 4 <= n; e += 4) {
        const float2 q0 = ern[s + e + 0];
        const float2 q1 = ern[s + e + 1];
        const float2 q2 = ern[s + e + 2];
        const float2 q3 = ern[s + e + 3];
        const float2 v0 = Hp[(long)__float_as_int(q0.x) * 64 + lane];
        const float2 v1 = Hp[(long)__float_as_int(q1.x) * 64 + lane];
        const float2 v2 = Hp[(long)__float_as_int(q2.x) * 64 + lane];
        const float2 v3 = Hp[(long)__float_as_int(q3.x) * 64 + lane];
        ax = fmaf(q0.y, v0.x, ax); ay = fmaf(q0.y, v0.y, ay);
        ax = fmaf(q1.y, v1.x, ax); ay = fmaf(q1.y, v1.y, ay);
        ax = fmaf(q2.y, v2.x, ax); ay = fmaf(q2.y, v2.y, ay);
        ax = fmaf(q3.y, v3.x, ax); ay = fmaf(q3.y, v3.y, ay);
    }
    for (; e < n; ++e) {
        const float2 q = ern[s + e];
        const float2 v = Hp[(long)__float_as_int(q.x) * 64 + lane];
        ax = fmaf(q.y, v.x, ax); ay = fmaf(q.y, v.y, ay);
    }

    const float ux = fmaxf(ax + bias[2 * lane], 0.f);
    const float uy = fmaxf(ay + bias[2 * lane + 1], 0.f);
    float s1 = ux + uy, s2 = ux * ux + uy * uy;
#pragma unroll
    for (int o = 32; o >= 1; o >>= 1) {
        s1 += __shfl_xor(s1, o);
        s2 += __shfl_xor(s2, o);
    }
    const float mu = s1 * (1.f / 128.f);
    const float var = s2 * (1.f / 128.f) - mu * mu;
    const float rs = rsqrtf(var + EPSV);
    float2 o2;
    o2.x = (ux - mu) * rs * gm[2 * lane] + bt[2 * lane];
    o2.y = (uy - mu) * rs * gm[2 * lane + 1] + bt[2 * lane + 1];
    reinterpret_cast<float2*>(Out)[wv * 64 + lane] = o2;
}

// D=64: one wave per node, 1 float per lane; fused mean-pool atomics.
__global__ __launch_bounds__(256) void k_gat64(const float* __restrict__ H,
                                               const int* __restrict__ off,
                                               const int* __restrict__ cnt,
                                               const float2* __restrict__ ern,
                                               const float* __restrict__ dinv,
                                               const float* __restrict__ bias,
                                               const float* __restrict__ gm,
                                               const float* __restrict__ bt,
                                               const int* __restrict__ batch,
                                               float* __restrict__ pool, int N) {
    const long wv = ((long)blockIdx.x * 256 + threadIdx.x) >> 6;
    const int lane = threadIdx.x & 63;
    if (wv >= N) return;
    const int s = off[wv];
    const int n = cnt[wv];
    const float d = dinv[wv];

    float acc = H[wv * 64 + lane] * d * d;
    int e = 0;
    for (; e + 4 <= n; e += 4) {
        const float2 q0 = ern[s + e + 0];
        const float2 q1 = ern[s + e + 1];
        const float2 q2 = ern[s + e + 2];
        const float2 q3 = ern[s + e + 3];
        const float v0 = H[(long)__float_as_int(q0.x) * 64 + lane];
        const float v1 = H[(long)__float_as_int(q1.x) * 64 + lane];
        const float v2 = H[(long)__float_as_int(q2.x) * 64 + lane];
        const float v3 = H[(long)__float_as_int(q3.x) * 64 + lane];
        acc = fmaf(q0.y, v0, acc);
        acc = fmaf(q1.y, v1, acc);
        acc = fmaf(q2.y, v2, acc);
        acc = fmaf(q3.y, v3, acc);
    }
    for (; e < n; ++e) {
        const float2 q = ern[s + e];
        acc = fmaf(q.y, H[(long)__float_as_int(q.x) * 64 + lane], acc);
    }

    const float u = fmaxf(acc + bias[lane], 0.f);
    float s1 = u, s2 = u * u;
#pragma unroll
    for (int o = 32; o >= 1; o >>= 1) {
        s1 += __shfl_xor(s1, o);
        s2 += __shfl_xor(s2, o);
    }
    const float mu = s1 * (1.f / 64.f);
    const float var = s2 * (1.f / 64.f) - mu * mu;
    const float rs = rsqrtf(var + EPSV);
    const float val = (u - mu) * rs * gm[lane] + bt[lane];

    const int b = batch[wv];
    unsafeAtomicAdd(&pool[b * 64 + lane], val);
    if (lane == 0) unsafeAtomicAdd(&pool[64 * 64 + b], 1.0f);
}

__global__ __launch_bounds__(256) void k_final(const float* __restrict__ pool,
                                               float* __restrict__ out) {
    const int i = blockIdx.x * 256 + threadIdx.x;
    if (i < 4096) {
        const int g = i >> 6;
        const float cnt = fmaxf(pool[64 * 64 + g], 1.0f);
        const float v = pool[i] / cnt;
        out[i] = 1.f / (1.f + expf(-v));
    }
}

// -------------------------------------------------------------- launch ----
extern "C" void kernel_launch(void* const* d_in, const int* in_sizes, int n_in,
                              void* d_out, int out_size, void* d_ws, size_t ws_size,
                              hipStream_t stream) {
    const float* x   = (const float*)d_in[0];
    const int*   ei  = (const int*)d_in[1];
    const float* ew  = (const float*)d_in[2];
    const int*   bat = (const int*)d_in[3];
    const float* W1  = (const float*)d_in[4];
    const float* b1  = (const float*)d_in[5];
    const float* g1  = (const float*)d_in[6];
    const float* bt1 = (const float*)d_in[7];
    const float* W2  = (const float*)d_in[8];
    const float* b2  = (const float*)d_in[9];
    const float* g2  = (const float*)d_in[10];
    const float* bt2 = (const float*)d_in[11];
    const int N = in_sizes[3];
    const int E = in_sizes[2];

    float* ws     = (float*)d_ws;
    float* A      = ws;                    // [N][128] h1; reused as h2 [N][64]
    float* B      = A + (long)N * 128;     // [N][128] ln1 out -> x2
    float* deg    = B + (long)N * 128;     // [N] deg -> dinv (in place)
    int*   cnt    = (int*)(deg + N);       // [N]
    int*   off    = cnt + N;               // [N]
    int*   cursor = off + N;               // [N]
    float2* ern   = (float2*)(cursor + N); // [E] (row_bits, norm)
    float* pool   = (float*)(ern + E);     // [64*64 + 64]

    const int nbN = (N + 255) / 256;
    const int nbE = (E + 255) / 256;
    const int nbW = (int)(((long)N * 64 + 255) / 256);

    k_init<<<nbN, 256, 0, stream>>>(deg, cnt, pool, N);
    k_degacc<<<nbE, 256, 0, stream>>>(ei, ew, deg, cnt, E);
    k_dinv<<<nbN, 256, 0, stream>>>(deg, N);
    k_scan<<<1, 256, 0, stream>>>(cnt, off, cursor, N);
    k_fill<<<nbE, 256, 0, stream>>>(ei, ew, deg, cursor, ern, E);

    // layer 1: GCNConv(256->128) + ReLU + LN
    k_gemm<256, 128><<<(N + 31) / 32, 256, 0, stream>>>(x, W1, A, N);
    k_gat128<<<nbW, 256, 0, stream>>>(A, off, cnt, ern, deg, b1, g1, bt1, B, N);

    // layer 2: GCNConv(128->64) + ReLU + LN + pool
    k_gemm<128, 64><<<(N + 31) / 32, 256, 0, stream>>>(B, W2, A, N);
    k_gat64<<<nbW, 256, 0, stream>>>(A, off, cnt, ern, deg, b2, g2, bt2, bat, pool, N);

    k_final<<<16, 256, 0, stream>>>(pool, (float*)d_out);
}

// Round 3
// 614.066 us; speedup vs baseline: 8.2226x; 2.7742x over previous
//
#include <hip/hip_runtime.h>
#include <cstdint>

#define EPSV 1e-5f

// ---------------------------------------------------------------- init ----
__global__ __launch_bounds__(256) void k_init(float* __restrict__ deg,
                                              int* __restrict__ cnt,
                                              float* __restrict__ pool, int N) {
    const int i = blockIdx.x * 256 + threadIdx.x;
    if (i < N) { deg[i] = 1.0f; cnt[i] = 0; }  // self-loop weight, edge histogram
    if (i < 64 * 64 + 64) pool[i] = 0.0f;      // pooled sums + counts
}

__global__ __launch_bounds__(256) void k_degacc(const int* __restrict__ ei,
                                                const float* __restrict__ ew,
                                                float* __restrict__ deg,
                                                int* __restrict__ cnt, int E) {
    const int e = blockIdx.x * 256 + threadIdx.x;
    if (e < E) {
        const int c = ei[E + e];
        unsafeAtomicAdd(&deg[c], ew[e]);
        atomicAdd(&cnt[c], 1);
    }
}

__global__ __launch_bounds__(256) void k_dinv(float* __restrict__ deg, int N) {
    const int i = blockIdx.x * 256 + threadIdx.x;
    if (i < N) {
        const float d = deg[i];
        deg[i] = d > 0.f ? rsqrtf(fmaxf(d, EPSV)) : 0.f;
    }
}

// ------------------------------------------------------- prefix scan ------
// 3-kernel parallel scan: block-reduce -> scan partials -> block-scan+add.
__global__ __launch_bounds__(256) void k_scan1(const int* __restrict__ cnt,
                                               int* __restrict__ bsum, int N) {
    __shared__ int ws[4];
    const int i = blockIdx.x * 256 + threadIdx.x;
    int v = (i < N) ? cnt[i] : 0;
#pragma unroll
    for (int o = 32; o >= 1; o >>= 1) v += __shfl_xor(v, o);
    if ((threadIdx.x & 63) == 0) ws[threadIdx.x >> 6] = v;
    __syncthreads();
    if (threadIdx.x == 0) bsum[blockIdx.x] = ws[0] + ws[1] + ws[2] + ws[3];
}

__global__ __launch_bounds__(256) void k_scan2(int* __restrict__ bsum, int NB) {
    __shared__ int carry;
    __shared__ int wsum[4];
    if (threadIdx.x == 0) carry = 0;
    __syncthreads();
    const int lane = threadIdx.x & 63, w = threadIdx.x >> 6;
    for (int base = 0; base < NB; base += 256) {
        const int i = base + threadIdx.x;
        const int v = (i < NB) ? bsum[i] : 0;
        int s = v;
#pragma unroll
        for (int o = 1; o < 64; o <<= 1) {
            const int t = __shfl_up(s, o);
            if (lane >= o) s += t;
        }
        if (lane == 63) wsum[w] = s;
        __syncthreads();
        int add = carry;
        for (int k = 0; k < w; ++k) add += wsum[k];
        const int tot = wsum[0] + wsum[1] + wsum[2] + wsum[3];
        if (i < NB) bsum[i] = add + s - v;
        __syncthreads();
        if (threadIdx.x == 0) carry += tot;
        __syncthreads();
    }
}

__global__ __launch_bounds__(256) void k_scan3(const int* __restrict__ cnt,
                                               const int* __restrict__ bsum,
                                               int* __restrict__ off,
                                               int* __restrict__ cursor, int N) {
    __shared__ int wsum[4];
    const int i = blockIdx.x * 256 + threadIdx.x;
    const int v = (i < N) ? cnt[i] : 0;
    const int lane = threadIdx.x & 63, w = threadIdx.x >> 6;
    int s = v;
#pragma unroll
    for (int o = 1; o < 64; o <<= 1) {
        const int t = __shfl_up(s, o);
        if (lane >= o) s += t;
    }
    if (lane == 63) wsum[w] = s;
    __syncthreads();
    int add = bsum[blockIdx.x];
    for (int k = 0; k < w; ++k) add += wsum[k];
    if (i < N) {
        const int excl = add + s - v;
        off[i] = excl;
        cursor[i] = excl;
    }
}

// Scatter edges into CSR: ern[p] = (row_bits, norm)
__global__ __launch_bounds__(256) void k_fill(const int* __restrict__ ei,
                                              const float* __restrict__ ew,
                                              const float* __restrict__ dinv,
                                              int* __restrict__ cursor,
                                              float2* __restrict__ ern, int E) {
    const int e = blockIdx.x * 256 + threadIdx.x;
    if (e >= E) return;
    const int r = ei[e];
    const int c = ei[E + e];
    const int p = atomicAdd(&cursor[c], 1);
    ern[p] = make_float2(__int_as_float(r), dinv[r] * ew[e] * dinv[c]);
}

// ---------------------------------------------------------------- GEMM ----
// H[N][NOUT] = X[N][K] @ W[K][NOUT].
template <int K, int NOUT>
__global__ __launch_bounds__(256) void k_gemm(const float* __restrict__ X,
                                              const float* __restrict__ W,
                                              float* __restrict__ H, int N) {
    constexpr int NT = 32;
    constexpr int CPL = NOUT / 64;
    __shared__ float xs[NT * K];
    const int tid = threadIdx.x;
    const long base = (long)blockIdx.x * NT;

    const float4* Xg = reinterpret_cast<const float4*>(X + base * K);
    float4* xs4 = reinterpret_cast<float4*>(xs);
    constexpr int TOT4 = NT * K / 4;
    const long max4 = ((long)N * K) / 4 - base * (K / 4);
#pragma unroll
    for (int i = 0; i < TOT4 / 256; ++i) {
        const int idx = tid + i * 256;
        if (idx < max4) xs4[idx] = Xg[idx];
    }
    __syncthreads();

    const int wave = tid >> 6, lane = tid & 63;
    float acc[8][CPL];
#pragma unroll
    for (int n = 0; n < 8; ++n)
#pragma unroll
        for (int c = 0; c < CPL; ++c) acc[n][c] = 0.f;

    const float* xw = xs + wave * 8 * K;
    for (int k4 = 0; k4 < K / 4; ++k4) {
        float wv[4][CPL];
#pragma unroll
        for (int kk = 0; kk < 4; ++kk)
#pragma unroll
            for (int c = 0; c < CPL; ++c)
                wv[kk][c] = W[(k4 * 4 + kk) * NOUT + c * 64 + lane];
#pragma unroll
        for (int n = 0; n < 8; ++n) {
            const float4 xv = *reinterpret_cast<const float4*>(xw + n * K + k4 * 4);
#pragma unroll
            for (int c = 0; c < CPL; ++c) {
                acc[n][c] += xv.x * wv[0][c];
                acc[n][c] += xv.y * wv[1][c];
                acc[n][c] += xv.z * wv[2][c];
                acc[n][c] += xv.w * wv[3][c];
            }
        }
    }

#pragma unroll
    for (int n = 0; n < 8; ++n) {
        const long node = base + wave * 8 + n;
        if (node < N)
#pragma unroll
            for (int c = 0; c < CPL; ++c)
                H[node * NOUT + c * 64 + lane] = acc[n][c];
    }
}

// --------------------------------- gather + bias + ReLU + LayerNorm -------
// D=128: one wave per node, float2 per lane; 8-wide MLP unroll.
__global__ __launch_bounds__(256) void k_gat128(const float* __restrict__ H,
                                                const int* __restrict__ off,
                                                const int* __restrict__ cnt,
                                                const float2* __restrict__ ern,
                                                const float* __restrict__ dinv,
                                                const float* __restrict__ bias,
                                                const float* __restrict__ gm,
                                                const float* __restrict__ bt,
                                                float* __restrict__ Out, int N) {
    const long wv = ((long)blockIdx.x * 256 + threadIdx.x) >> 6;
    const int lane = threadIdx.x & 63;
    if (wv >= N) return;
    const int s = off[wv];
    const int n = cnt[wv];
    const float d = dinv[wv];
    const float2* Hp = reinterpret_cast<const float2*>(H);

    const float2 h0 = Hp[wv * 64 + lane];
    float ax = h0.x * d * d, ay = h0.y * d * d;

    int e = 0;
    for (; e + 8 <= n; e += 8) {
        float2 q[8];
#pragma unroll
        for (int j = 0; j < 8; ++j) q[j] = ern[s + e + j];
        float2 v[8];
#pragma unroll
        for (int j = 0; j < 8; ++j)
            v[j] = Hp[(long)__float_as_int(q[j].x) * 64 + lane];
#pragma unroll
        for (int j = 0; j < 8; ++j) {
            ax = fmaf(q[j].y, v[j].x, ax);
            ay = fmaf(q[j].y, v[j].y, ay);
        }
    }
    for (; e < n; ++e) {
        const float2 q = ern[s + e];
        const float2 v = Hp[(long)__float_as_int(q.x) * 64 + lane];
        ax = fmaf(q.y, v.x, ax);
        ay = fmaf(q.y, v.y, ay);
    }

    const float ux = fmaxf(ax + bias[2 * lane], 0.f);
    const float uy = fmaxf(ay + bias[2 * lane + 1], 0.f);
    float s1 = ux + uy, s2 = ux * ux + uy * uy;
#pragma unroll
    for (int o = 32; o >= 1; o >>= 1) {
        s1 += __shfl_xor(s1, o);
        s2 += __shfl_xor(s2, o);
    }
    const float mu = s1 * (1.f / 128.f);
    const float var = s2 * (1.f / 128.f) - mu * mu;
    const float rs = rsqrtf(var + EPSV);
    float2 o2;
    o2.x = (ux - mu) * rs * gm[2 * lane] + bt[2 * lane];
    o2.y = (uy - mu) * rs * gm[2 * lane + 1] + bt[2 * lane + 1];
    reinterpret_cast<float2*>(Out)[wv * 64 + lane] = o2;
}

// D=64: one wave per node; 8-wide MLP unroll; writes LN output (no pool).
__global__ __launch_bounds__(256) void k_gat64(const float* __restrict__ H,
                                               const int* __restrict__ off,
                                               const int* __restrict__ cnt,
                                               const float2* __restrict__ ern,
                                               const float* __restrict__ dinv,
                                               const float* __restrict__ bias,
                                               const float* __restrict__ gm,
                                               const float* __restrict__ bt,
                                               float* __restrict__ Out, int N) {
    const long wv = ((long)blockIdx.x * 256 + threadIdx.x) >> 6;
    const int lane = threadIdx.x & 63;
    if (wv >= N) return;
    const int s = off[wv];
    const int n = cnt[wv];
    const float d = dinv[wv];

    float acc = H[wv * 64 + lane] * d * d;
    int e = 0;
    for (; e + 8 <= n; e += 8) {
        float2 q[8];
#pragma unroll
        for (int j = 0; j < 8; ++j) q[j] = ern[s + e + j];
        float v[8];
#pragma unroll
        for (int j = 0; j < 8; ++j)
            v[j] = H[(long)__float_as_int(q[j].x) * 64 + lane];
#pragma unroll
        for (int j = 0; j < 8; ++j) acc = fmaf(q[j].y, v[j], acc);
    }
    for (; e < n; ++e) {
        const float2 q = ern[s + e];
        acc = fmaf(q.y, H[(long)__float_as_int(q.x) * 64 + lane], acc);
    }

    const float u = fmaxf(acc + bias[lane], 0.f);
    float s1 = u, s2 = u * u;
#pragma unroll
    for (int o = 32; o >= 1; o >>= 1) {
        s1 += __shfl_xor(s1, o);
        s2 += __shfl_xor(s2, o);
    }
    const float mu = s1 * (1.f / 64.f);
    const float var = s2 * (1.f / 64.f) - mu * mu;
    const float rs = rsqrtf(var + EPSV);
    Out[wv * 64 + lane] = (u - mu) * rs * gm[lane] + bt[lane];
}

// ---------------------------------------------------------------- pool ----
// batch is SORTED: each wave walks a contiguous chunk, register-accumulates
// per-graph partials, flushes one atomic instr per graph boundary.
__global__ __launch_bounds__(256) void k_pool(const float* __restrict__ C,
                                              const int* __restrict__ batch,
                                              float* __restrict__ pool,
                                              int N, int chunk) {
    const int wg = blockIdx.x * 4 + (threadIdx.x >> 6);
    const int lane = threadIdx.x & 63;
    long i = (long)wg * chunk;
    const long end = (i + chunk < (long)N) ? i + chunk : (long)N;
    if (i >= end) return;

    int cur = batch[i];
    float acc = 0.f;
    int cn = 0;
    while (i < end) {
        if (i + 8 <= end && batch[i + 7] == cur) {  // sorted -> all 8 == cur
            float v[8];
#pragma unroll
            for (int j = 0; j < 8; ++j) v[j] = C[(i + j) * 64 + lane];
            acc += ((v[0] + v[1]) + (v[2] + v[3])) + ((v[4] + v[5]) + (v[6] + v[7]));
            cn += 8;
            i += 8;
            continue;
        }
        const int b = batch[i];
        if (b != cur) {
            unsafeAtomicAdd(&pool[cur * 64 + lane], acc);
            if (lane == 0) unsafeAtomicAdd(&pool[64 * 64 + cur], (float)cn);
            cur = b;
            acc = 0.f;
            cn = 0;
        }
        acc += C[i * 64 + lane];
        ++cn;
        ++i;
    }
    unsafeAtomicAdd(&pool[cur * 64 + lane], acc);
    if (lane == 0) unsafeAtomicAdd(&pool[64 * 64 + cur], (float)cn);
}

__global__ __launch_bounds__(256) void k_final(const float* __restrict__ pool,
                                               float* __restrict__ out) {
    const int i = blockIdx.x * 256 + threadIdx.x;
    if (i < 4096) {
        const int g = i >> 6;
        const float cnt = fmaxf(pool[64 * 64 + g], 1.0f);
        const float v = pool[i] / cnt;
        out[i] = 1.f / (1.f + expf(-v));
    }
}

// -------------------------------------------------------------- launch ----
extern "C" void kernel_launch(void* const* d_in, const int* in_sizes, int n_in,
                              void* d_out, int out_size, void* d_ws, size_t ws_size,
                              hipStream_t stream) {
    const float* x   = (const float*)d_in[0];
    const int*   ei  = (const int*)d_in[1];
    const float* ew  = (const float*)d_in[2];
    const int*   bat = (const int*)d_in[3];
    const float* W1  = (const float*)d_in[4];
    const float* b1  = (const float*)d_in[5];
    const float* g1  = (const float*)d_in[6];
    const float* bt1 = (const float*)d_in[7];
    const float* W2  = (const float*)d_in[8];
    const float* b2  = (const float*)d_in[9];
    const float* g2  = (const float*)d_in[10];
    const float* bt2 = (const float*)d_in[11];
    const int N = in_sizes[3];
    const int E = in_sizes[2];
    const int NB = (N + 255) / 256;

    float* ws     = (float*)d_ws;
    float* A      = ws;                    // [N][128] h1; reused as h2 [N][64]
    float* B      = A + (long)N * 128;     // [N][128] ln1 out -> x2; then ln2 out [N][64]
    float* deg    = B + (long)N * 128;     // [N] deg -> dinv (in place)
    int*   cnt    = (int*)(deg + N);       // [N]
    int*   off    = cnt + N;               // [N]
    int*   cursor = off + N;               // [N]
    int*   bsum   = cursor + N;            // [NB]
    float2* ern   = (float2*)(bsum + NB + ((NB & 1) ? 1 : 0)); // [E], 8B aligned
    float* pool   = (float*)(ern + E);     // [64*64 + 64]

    const int nbE = (E + 255) / 256;
    const int nbW = (int)(((long)N * 64 + 255) / 256);

    k_init<<<NB, 256, 0, stream>>>(deg, cnt, pool, N);
    k_degacc<<<nbE, 256, 0, stream>>>(ei, ew, deg, cnt, E);
    k_dinv<<<NB, 256, 0, stream>>>(deg, N);
    k_scan1<<<NB, 256, 0, stream>>>(cnt, bsum, N);
    k_scan2<<<1, 256, 0, stream>>>(bsum, NB);
    k_scan3<<<NB, 256, 0, stream>>>(cnt, bsum, off, cursor, N);
    k_fill<<<nbE, 256, 0, stream>>>(ei, ew, deg, cursor, ern, E);

    // layer 1: GCNConv(256->128) + ReLU + LN
    k_gemm<256, 128><<<(N + 31) / 32, 256, 0, stream>>>(x, W1, A, N);
    k_gat128<<<nbW, 256, 0, stream>>>(A, off, cnt, ern, deg, b1, g1, bt1, B, N);

    // layer 2: GCNConv(128->64) + ReLU + LN
    k_gemm<128, 64><<<(N + 31) / 32, 256, 0, stream>>>(B, W2, A, N);
    k_gat64<<<nbW, 256, 0, stream>>>(A, off, cnt, ern, deg, b2, g2, bt2, B, N);

    // global mean pool + sigmoid
    const int chunk = (N + 1023) / 1024;
    k_pool<<<256, 256, 0, stream>>>(B, bat, pool, N, chunk);
    k_final<<<16, 256, 0, stream>>>(pool, (float*)d_out);
}

// Round 4
// 554.717 us; speedup vs baseline: 9.1023x; 1.1070x over previous
//
#include <hip/hip_runtime.h>
#include <cstdint>

#define EPSV 1e-5f

typedef __bf16 bf16x8 __attribute__((ext_vector_type(8)));
typedef __bf16 bf16x2 __attribute__((ext_vector_type(2)));
typedef float  f32x4  __attribute__((ext_vector_type(4)));

// ---------------------------------------------------------------- init ----
__global__ __launch_bounds__(256) void k_init(float* __restrict__ deg,
                                              int* __restrict__ cnt,
                                              float* __restrict__ pool, int N) {
    const int i = blockIdx.x * 256 + threadIdx.x;
    if (i < N) { deg[i] = 1.0f; cnt[i] = 0; }
    if (i < 64 * 64 + 64) pool[i] = 0.0f;
}

__global__ __launch_bounds__(256) void k_degacc(const int* __restrict__ ei,
                                                const float* __restrict__ ew,
                                                float* __restrict__ deg,
                                                int* __restrict__ cnt, int E) {
    const int e = blockIdx.x * 256 + threadIdx.x;
    if (e < E) {
        const int c = ei[E + e];
        unsafeAtomicAdd(&deg[c], ew[e]);
        atomicAdd(&cnt[c], 1);
    }
}

__global__ __launch_bounds__(256) void k_dinv(float* __restrict__ deg, int N) {
    const int i = blockIdx.x * 256 + threadIdx.x;
    if (i < N) {
        const float d = deg[i];
        deg[i] = d > 0.f ? rsqrtf(fmaxf(d, EPSV)) : 0.f;
    }
}

// ------------------------------------------------------- prefix scan ------
__global__ __launch_bounds__(256) void k_scan1(const int* __restrict__ cnt,
                                               int* __restrict__ bsum, int N) {
    __shared__ int ws[4];
    const int i = blockIdx.x * 256 + threadIdx.x;
    int v = (i < N) ? cnt[i] : 0;
#pragma unroll
    for (int o = 32; o >= 1; o >>= 1) v += __shfl_xor(v, o);
    if ((threadIdx.x & 63) == 0) ws[threadIdx.x >> 6] = v;
    __syncthreads();
    if (threadIdx.x == 0) bsum[blockIdx.x] = ws[0] + ws[1] + ws[2] + ws[3];
}

__global__ __launch_bounds__(256) void k_scan2(int* __restrict__ bsum, int NB) {
    __shared__ int carry;
    __shared__ int wsum[4];
    if (threadIdx.x == 0) carry = 0;
    __syncthreads();
    const int lane = threadIdx.x & 63, w = threadIdx.x >> 6;
    for (int base = 0; base < NB; base += 256) {
        const int i = base + threadIdx.x;
        const int v = (i < NB) ? bsum[i] : 0;
        int s = v;
#pragma unroll
        for (int o = 1; o < 64; o <<= 1) {
            const int t = __shfl_up(s, o);
            if (lane >= o) s += t;
        }
        if (lane == 63) wsum[w] = s;
        __syncthreads();
        int add = carry;
        for (int k = 0; k < w; ++k) add += wsum[k];
        const int tot = wsum[0] + wsum[1] + wsum[2] + wsum[3];
        if (i < NB) bsum[i] = add + s - v;
        __syncthreads();
        if (threadIdx.x == 0) carry += tot;
        __syncthreads();
    }
}

__global__ __launch_bounds__(256) void k_scan3(const int* __restrict__ cnt,
                                               const int* __restrict__ bsum,
                                               int* __restrict__ off,
                                               int* __restrict__ cursor, int N) {
    __shared__ int wsum[4];
    const int i = blockIdx.x * 256 + threadIdx.x;
    const int v = (i < N) ? cnt[i] : 0;
    const int lane = threadIdx.x & 63, w = threadIdx.x >> 6;
    int s = v;
#pragma unroll
    for (int o = 1; o < 64; o <<= 1) {
        const int t = __shfl_up(s, o);
        if (lane >= o) s += t;
    }
    if (lane == 63) wsum[w] = s;
    __syncthreads();
    int add = bsum[blockIdx.x];
    for (int k = 0; k < w; ++k) add += wsum[k];
    if (i < N) {
        const int excl = add + s - v;
        off[i] = excl;
        cursor[i] = excl;
    }
}

// Scatter edges into CSR: ern[p] = (row_bits, norm)
__global__ __launch_bounds__(256) void k_fill(const int* __restrict__ ei,
                                              const float* __restrict__ ew,
                                              const float* __restrict__ dinv,
                                              int* __restrict__ cursor,
                                              float2* __restrict__ ern, int E) {
    const int e = blockIdx.x * 256 + threadIdx.x;
    if (e >= E) return;
    const int r = ei[e];
    const int c = ei[E + e];
    const int p = atomicAdd(&cursor[c], 1);
    ern[p] = make_float2(__int_as_float(r), dinv[r] * ew[e] * dinv[c]);
}

// ----------------------------------------------------- W transpose+cvt ----
// Wt[c][k] = (bf16) W[k][c]
__global__ __launch_bounds__(256) void k_wcvt(const float* __restrict__ W,
                                              __bf16* __restrict__ Wt,
                                              int K, int NOUT) {
    const int idx = blockIdx.x * 256 + threadIdx.x;
    if (idx >= K * NOUT) return;
    const int c = idx / K;
    const int k = idx - c * K;
    Wt[idx] = (__bf16)W[k * NOUT + c];
}

// ----------------------------------------------------------- MFMA GEMM ----
// H[N][NOUT] = X[N][K] @ W[K][NOUT], Wt is [NOUT][K] bf16.
// Block: 4 waves x 16 rows = 64-row tile; each wave computes all NOUT cols.
// Fragment maps (m89-verified): A row=lane&15, k=(lane>>4)*8+j;
// B col=lane&15, same k; D row=(lane>>4)*4+r, col=lane&15.
template <int K, int NOUT, bool ABF16>
__global__ __launch_bounds__(256) void k_mm(const void* __restrict__ Xv,
                                            const __bf16* __restrict__ Wt,
                                            float* __restrict__ H, int N) {
    constexpr int NCB = NOUT / 16;  // col fragments
    constexpr int NKB = K / 32;     // K steps
    const int tid = threadIdx.x;
    const int w = tid >> 6, l = tid & 63;
    const int r0 = l & 15, kq = l >> 4;
    const long base = (long)blockIdx.x * 64 + w * 16;
    const long arow = base + r0;
    const long lrow = arow < N ? arow : (long)N - 1;

    f32x4 acc[NCB];
#pragma unroll
    for (int cb = 0; cb < NCB; ++cb) acc[cb] = (f32x4){0.f, 0.f, 0.f, 0.f};

#pragma unroll 2
    for (int kb = 0; kb < NKB; ++kb) {
        const int koff = kb * 32 + kq * 8;
        bf16x8 af;
        if constexpr (ABF16) {
            af = *reinterpret_cast<const bf16x8*>((const __bf16*)Xv + lrow * K + koff);
        } else {
            const float* xp = (const float*)Xv + lrow * K + koff;
            const float4 a0 = *reinterpret_cast<const float4*>(xp);
            const float4 a1 = *reinterpret_cast<const float4*>(xp + 4);
            af[0] = (__bf16)a0.x; af[1] = (__bf16)a0.y;
            af[2] = (__bf16)a0.z; af[3] = (__bf16)a0.w;
            af[4] = (__bf16)a1.x; af[5] = (__bf16)a1.y;
            af[6] = (__bf16)a1.z; af[7] = (__bf16)a1.w;
        }
#pragma unroll
        for (int cb = 0; cb < NCB; ++cb) {
            const bf16x8 bf =
                *reinterpret_cast<const bf16x8*>(Wt + (long)(cb * 16 + r0) * K + koff);
            acc[cb] = __builtin_amdgcn_mfma_f32_16x16x32_bf16(af, bf, acc[cb], 0, 0, 0);
        }
    }

    const int orow = kq * 4;
#pragma unroll
    for (int cb = 0; cb < NCB; ++cb)
#pragma unroll
        for (int r = 0; r < 4; ++r) {
            const long gr = base + orow + r;
            if (gr < N) H[gr * NOUT + cb * 16 + r0] = acc[cb][r];
        }
}

// --------------------------------- gather + bias + ReLU + LayerNorm -------
// D=128: one wave per node, float2 per lane; writes bf16 (gemm2 input).
__global__ __launch_bounds__(256) void k_gat128(const float* __restrict__ H,
                                                const int* __restrict__ off,
                                                const int* __restrict__ cnt,
                                                const float2* __restrict__ ern,
                                                const float* __restrict__ dinv,
                                                const float* __restrict__ bias,
                                                const float* __restrict__ gm,
                                                const float* __restrict__ bt,
                                                __bf16* __restrict__ Out, int N) {
    const long wv = ((long)blockIdx.x * 256 + threadIdx.x) >> 6;
    const int lane = threadIdx.x & 63;
    if (wv >= N) return;
    const int s = off[wv];
    const int n = cnt[wv];
    const float d = dinv[wv];
    const float2* Hp = reinterpret_cast<const float2*>(H);

    const float2 h0 = Hp[wv * 64 + lane];
    float ax = h0.x * d * d, ay = h0.y * d * d;

    int e = 0;
    for (; e + 8 <= n; e += 8) {
        float2 q[8];
#pragma unroll
        for (int j = 0; j < 8; ++j) q[j] = ern[s + e + j];
        float2 v[8];
#pragma unroll
        for (int j = 0; j < 8; ++j)
            v[j] = Hp[(long)__float_as_int(q[j].x) * 64 + lane];
#pragma unroll
        for (int j = 0; j < 8; ++j) {
            ax = fmaf(q[j].y, v[j].x, ax);
            ay = fmaf(q[j].y, v[j].y, ay);
        }
    }
    for (; e < n; ++e) {
        const float2 q = ern[s + e];
        const float2 v = Hp[(long)__float_as_int(q.x) * 64 + lane];
        ax = fmaf(q.y, v.x, ax);
        ay = fmaf(q.y, v.y, ay);
    }

    const float ux = fmaxf(ax + bias[2 * lane], 0.f);
    const float uy = fmaxf(ay + bias[2 * lane + 1], 0.f);
    float s1 = ux + uy, s2 = ux * ux + uy * uy;
#pragma unroll
    for (int o = 32; o >= 1; o >>= 1) {
        s1 += __shfl_xor(s1, o);
        s2 += __shfl_xor(s2, o);
    }
    const float mu = s1 * (1.f / 128.f);
    const float var = s2 * (1.f / 128.f) - mu * mu;
    const float rs = rsqrtf(var + EPSV);
    bf16x2 ob;
    ob[0] = (__bf16)((ux - mu) * rs * gm[2 * lane] + bt[2 * lane]);
    ob[1] = (__bf16)((uy - mu) * rs * gm[2 * lane + 1] + bt[2 * lane + 1]);
    reinterpret_cast<bf16x2*>(Out)[wv * 64 + lane] = ob;
}

// D=64: one wave per node; writes fp32 LN output.
__global__ __launch_bounds__(256) void k_gat64(const float* __restrict__ H,
                                               const int* __restrict__ off,
                                               const int* __restrict__ cnt,
                                               const float2* __restrict__ ern,
                                               const float* __restrict__ dinv,
                                               const float* __restrict__ bias,
                                               const float* __restrict__ gm,
                                               const float* __restrict__ bt,
                                               float* __restrict__ Out, int N) {
    const long wv = ((long)blockIdx.x * 256 + threadIdx.x) >> 6;
    const int lane = threadIdx.x & 63;
    if (wv >= N) return;
    const int s = off[wv];
    const int n = cnt[wv];
    const float d = dinv[wv];

    float acc = H[wv * 64 + lane] * d * d;
    int e = 0;
    for (; e + 8 <= n; e += 8) {
        float2 q[8];
#pragma unroll
        for (int j = 0; j < 8; ++j) q[j] = ern[s + e + j];
        float v[8];
#pragma unroll
        for (int j = 0; j < 8; ++j)
            v[j] = H[(long)__float_as_int(q[j].x) * 64 + lane];
#pragma unroll
        for (int j = 0; j < 8; ++j) acc = fmaf(q[j].y, v[j], acc);
    }
    for (; e < n; ++e) {
        const float2 q = ern[s + e];
        acc = fmaf(q.y, H[(long)__float_as_int(q.x) * 64 + lane], acc);
    }

    const float u = fmaxf(acc + bias[lane], 0.f);
    float s1 = u, s2 = u * u;
#pragma unroll
    for (int o = 32; o >= 1; o >>= 1) {
        s1 += __shfl_xor(s1, o);
        s2 += __shfl_xor(s2, o);
    }
    const float mu = s1 * (1.f / 64.f);
    const float var = s2 * (1.f / 64.f) - mu * mu;
    const float rs = rsqrtf(var + EPSV);
    Out[wv * 64 + lane] = (u - mu) * rs * gm[lane] + bt[lane];
}

// ---------------------------------------------------------------- pool ----
__global__ __launch_bounds__(256) void k_pool(const float* __restrict__ C,
                                              const int* __restrict__ batch,
                                              float* __restrict__ pool,
                                              int N, int chunk) {
    const int wg = blockIdx.x * 4 + (threadIdx.x >> 6);
    const int lane = threadIdx.x & 63;
    long i = (long)wg * chunk;
    const long end = (i + chunk < (long)N) ? i + chunk : (long)N;
    if (i >= end) return;

    int cur = batch[i];
    float acc = 0.f;
    int cn = 0;
    while (i < end) {
        if (i + 8 <= end && batch[i + 7] == cur) {
            float v[8];
#pragma unroll
            for (int j = 0; j < 8; ++j) v[j] = C[(i + j) * 64 + lane];
            acc += ((v[0] + v[1]) + (v[2] + v[3])) + ((v[4] + v[5]) + (v[6] + v[7]));
            cn += 8;
            i += 8;
            continue;
        }
        const int b = batch[i];
        if (b != cur) {
            unsafeAtomicAdd(&pool[cur * 64 + lane], acc);
            if (lane == 0) unsafeAtomicAdd(&pool[64 * 64 + cur], (float)cn);
            cur = b;
            acc = 0.f;
            cn = 0;
        }
        acc += C[i * 64 + lane];
        ++cn;
        ++i;
    }
    unsafeAtomicAdd(&pool[cur * 64 + lane], acc);
    if (lane == 0) unsafeAtomicAdd(&pool[64 * 64 + cur], (float)cn);
}

__global__ __launch_bounds__(256) void k_final(const float* __restrict__ pool,
                                               float* __restrict__ out) {
    const int i = blockIdx.x * 256 + threadIdx.x;
    if (i < 4096) {
        const int g = i >> 6;
        const float cnt = fmaxf(pool[64 * 64 + g], 1.0f);
        const float v = pool[i] / cnt;
        out[i] = 1.f / (1.f + expf(-v));
    }
}

// -------------------------------------------------------------- launch ----
extern "C" void kernel_launch(void* const* d_in, const int* in_sizes, int n_in,
                              void* d_out, int out_size, void* d_ws, size_t ws_size,
                              hipStream_t stream) {
    const float* x   = (const float*)d_in[0];
    const int*   ei  = (const int*)d_in[1];
    const float* ew  = (const float*)d_in[2];
    const int*   bat = (const int*)d_in[3];
    const float* W1  = (const float*)d_in[4];
    const float* b1  = (const float*)d_in[5];
    const float* g1  = (const float*)d_in[6];
    const float* bt1 = (const float*)d_in[7];
    const float* W2  = (const float*)d_in[8];
    const float* b2  = (const float*)d_in[9];
    const float* g2  = (const float*)d_in[10];
    const float* bt2 = (const float*)d_in[11];
    const int N = in_sizes[3];
    const int E = in_sizes[2];
    const int NB = (N + 255) / 256;

    float*  ws   = (float*)d_ws;
    float*  A    = ws;                         // [N*128] f32: h1; reused as h2 [N*64]
    __bf16* Bh   = (__bf16*)(A + (long)N * 128);   // [N*128] bf16: ln1 out
    float*  Cf   = (float*)(Bh + (long)N * 128);   // [N*64] f32: ln2 out
    float*  deg  = Cf + (long)N * 64;          // [N] deg -> dinv
    int*   cnt    = (int*)(deg + N);           // [N]
    int*   off    = cnt + N;                   // [N]
    int*   cursor = off + N;                   // [N]
    int*   bsum   = cursor + N;                // [NB]
    float2* ern   = (float2*)(bsum + NB + ((NB & 1) ? 1 : 0)); // [E]
    float* pool   = (float*)(ern + E);         // [64*64+64]
    __bf16* Wt1   = (__bf16*)(pool + 64 * 64 + 64);  // [128*256]
    __bf16* Wt2   = Wt1 + 128 * 256;                 // [64*128]

    const int nbE = (E + 255) / 256;
    const int nbW = (int)(((long)N * 64 + 255) / 256);

    k_init<<<NB, 256, 0, stream>>>(deg, cnt, pool, N);
    k_degacc<<<nbE, 256, 0, stream>>>(ei, ew, deg, cnt, E);
    k_dinv<<<NB, 256, 0, stream>>>(deg, N);
    k_scan1<<<NB, 256, 0, stream>>>(cnt, bsum, N);
    k_scan2<<<1, 256, 0, stream>>>(bsum, NB);
    k_scan3<<<NB, 256, 0, stream>>>(cnt, bsum, off, cursor, N);
    k_fill<<<nbE, 256, 0, stream>>>(ei, ew, deg, cursor, ern, E);
    k_wcvt<<<(256 * 128 + 255) / 256, 256, 0, stream>>>(W1, Wt1, 256, 128);
    k_wcvt<<<(128 * 64 + 255) / 256, 256, 0, stream>>>(W2, Wt2, 128, 64);

    // layer 1: GCNConv(256->128) + ReLU + LN
    k_mm<256, 128, false><<<(N + 63) / 64, 256, 0, stream>>>(x, Wt1, A, N);
    k_gat128<<<nbW, 256, 0, stream>>>(A, off, cnt, ern, deg, b1, g1, bt1, Bh, N);

    // layer 2: GCNConv(128->64) + ReLU + LN
    k_mm<128, 64, true><<<(N + 63) / 64, 256, 0, stream>>>(Bh, Wt2, A, N);
    k_gat64<<<nbW, 256, 0, stream>>>(A, off, cnt, ern, deg, b2, g2, bt2, Cf, N);

    // global mean pool + sigmoid
    const int chunk = (N + 1023) / 1024;
    k_pool<<<256, 256, 0, stream>>>(Cf, bat, pool, N, chunk);
    k_final<<<16, 256, 0, stream>>>(pool, (float*)d_out);
}

// Round 5
// 380.365 us; speedup vs baseline: 13.2747x; 1.4584x over previous
//
#include <hip/hip_runtime.h>
#include <cstdint>

#define EPSV 1e-5f

typedef __bf16 bf16x8 __attribute__((ext_vector_type(8)));
typedef __bf16 bf16x2 __attribute__((ext_vector_type(2)));
typedef float  f32x4  __attribute__((ext_vector_type(4)));
typedef unsigned long long u64;

// ------------------------------------------------- deg/cnt/rank in one ----
// dc[c] += (1<<40) | fix24(w); old>>40 = this edge's within-node rank.
__global__ __launch_bounds__(256) void k_degacc(const int* __restrict__ ei,
                                                const float* __restrict__ ew,
                                                u64* __restrict__ dc,
                                                unsigned short* __restrict__ rank,
                                                int E) {
    const int e = blockIdx.x * 256 + threadIdx.x;
    if (e < E) {
        const int c = ei[E + e];
        const u64 pack = (1ull << 40) | (u64)(ew[e] * 16777216.0f);
        const u64 old = atomicAdd(&dc[c], pack);
        rank[e] = (unsigned short)(old >> 40);
    }
}

// ------------------------------- unpack: dinv + cnt + block-sum (scan1) ---
__global__ __launch_bounds__(256) void k_scanA(const u64* __restrict__ dc,
                                               float* __restrict__ dinv,
                                               int* __restrict__ cnt,
                                               int* __restrict__ bsum, int N) {
    __shared__ int ws[4];
    const int i = blockIdx.x * 256 + threadIdx.x;
    int v = 0;
    if (i < N) {
        const u64 p = dc[i];
        v = (int)(p >> 40);
        const float deg = 1.0f + (float)(p & 0xFFFFFFFFFFull) * (1.0f / 16777216.0f);
        dinv[i] = rsqrtf(deg);  // deg >= 1 always (self loop)
        cnt[i] = v;
    }
#pragma unroll
    for (int o = 32; o >= 1; o >>= 1) v += __shfl_xor(v, o);
    if ((threadIdx.x & 63) == 0) ws[threadIdx.x >> 6] = v;
    __syncthreads();
    if (threadIdx.x == 0) bsum[blockIdx.x] = ws[0] + ws[1] + ws[2] + ws[3];
}

__global__ __launch_bounds__(256) void k_scan2(int* __restrict__ bsum, int NB) {
    __shared__ int carry;
    __shared__ int wsum[4];
    if (threadIdx.x == 0) carry = 0;
    __syncthreads();
    const int lane = threadIdx.x & 63, w = threadIdx.x >> 6;
    for (int base = 0; base < NB; base += 256) {
        const int i = base + threadIdx.x;
        const int v = (i < NB) ? bsum[i] : 0;
        int s = v;
#pragma unroll
        for (int o = 1; o < 64; o <<= 1) {
            const int t = __shfl_up(s, o);
            if (lane >= o) s += t;
        }
        if (lane == 63) wsum[w] = s;
        __syncthreads();
        int add = carry;
        for (int k = 0; k < w; ++k) add += wsum[k];
        const int tot = wsum[0] + wsum[1] + wsum[2] + wsum[3];
        if (i < NB) bsum[i] = add + s - v;
        __syncthreads();
        if (threadIdx.x == 0) carry += tot;
        __syncthreads();
    }
}

__global__ __launch_bounds__(256) void k_scan3(const int* __restrict__ cnt,
                                               const int* __restrict__ bsum,
                                               int* __restrict__ off, int N) {
    __shared__ int wsum[4];
    const int i = blockIdx.x * 256 + threadIdx.x;
    const int v = (i < N) ? cnt[i] : 0;
    const int lane = threadIdx.x & 63, w = threadIdx.x >> 6;
    int s = v;
#pragma unroll
    for (int o = 1; o < 64; o <<= 1) {
        const int t = __shfl_up(s, o);
        if (lane >= o) s += t;
    }
    if (lane == 63) wsum[w] = s;
    __syncthreads();
    int add = bsum[blockIdx.x];
    for (int k = 0; k < w; ++k) add += wsum[k];
    if (i < N) off[i] = add + s - v;
}

// ------------------- CSR fill, atomic-free: slot = off[c] + rank[e] -------
__global__ __launch_bounds__(256) void k_fill(const int* __restrict__ ei,
                                              const float* __restrict__ ew,
                                              const float* __restrict__ dinv,
                                              const int* __restrict__ off,
                                              const unsigned short* __restrict__ rank,
                                              float2* __restrict__ ern, int E) {
    const int e = blockIdx.x * 256 + threadIdx.x;
    if (e >= E) return;
    const int r = ei[e];
    const int c = ei[E + e];
    const int p = off[c] + (int)rank[e];
    ern[p] = make_float2(__int_as_float(r), dinv[r] * ew[e] * dinv[c]);
}

// ----------------------------------------------------- W transpose+cvt ----
// Both weights in one launch: Wt[c][k] = (bf16) W[k][c].
__global__ __launch_bounds__(256) void k_wcvt(const float* __restrict__ W1,
                                              __bf16* __restrict__ Wt1,
                                              const float* __restrict__ W2,
                                              __bf16* __restrict__ Wt2) {
    const int idx = blockIdx.x * 256 + threadIdx.x;
    if (idx < 128 * 256) {
        const int c = idx >> 8, k = idx & 255;          // K=256, NOUT=128
        Wt1[idx] = (__bf16)W1[k * 128 + c];
    } else if (idx < 128 * 256 + 64 * 128) {
        const int j = idx - 128 * 256;
        const int c = j >> 7, k = j & 127;              // K=128, NOUT=64
        Wt2[j] = (__bf16)W2[k * 64 + c];
    }
}

// ----------------------------------------------------------- MFMA GEMM ----
// H[N][NOUT] = X[N][K] @ W[K][NOUT] -> bf16 H. Wt is [NOUT][K] bf16.
// A row=lane&15, k=(lane>>4)*8+j; B col=lane&15; D row=(lane>>4)*4+r, col=lane&15.
template <int K, int NOUT, bool ABF16>
__global__ __launch_bounds__(256) void k_mm(const void* __restrict__ Xv,
                                            const __bf16* __restrict__ Wt,
                                            __bf16* __restrict__ H, int N) {
    constexpr int NCB = NOUT / 16;
    constexpr int NKB = K / 32;
    const int tid = threadIdx.x;
    const int w = tid >> 6, l = tid & 63;
    const int r0 = l & 15, kq = l >> 4;
    const long base = (long)blockIdx.x * 64 + w * 16;
    const long arow = base + r0;
    const long lrow = arow < N ? arow : (long)N - 1;

    f32x4 acc[NCB];
#pragma unroll
    for (int cb = 0; cb < NCB; ++cb) acc[cb] = (f32x4){0.f, 0.f, 0.f, 0.f};

#pragma unroll 2
    for (int kb = 0; kb < NKB; ++kb) {
        const int koff = kb * 32 + kq * 8;
        bf16x8 af;
        if constexpr (ABF16) {
            af = *reinterpret_cast<const bf16x8*>((const __bf16*)Xv + lrow * K + koff);
        } else {
            const float* xp = (const float*)Xv + lrow * K + koff;
            const float4 a0 = *reinterpret_cast<const float4*>(xp);
            const float4 a1 = *reinterpret_cast<const float4*>(xp + 4);
            af[0] = (__bf16)a0.x; af[1] = (__bf16)a0.y;
            af[2] = (__bf16)a0.z; af[3] = (__bf16)a0.w;
            af[4] = (__bf16)a1.x; af[5] = (__bf16)a1.y;
            af[6] = (__bf16)a1.z; af[7] = (__bf16)a1.w;
        }
#pragma unroll
        for (int cb = 0; cb < NCB; ++cb) {
            const bf16x8 bf =
                *reinterpret_cast<const bf16x8*>(Wt + (long)(cb * 16 + r0) * K + koff);
            acc[cb] = __builtin_amdgcn_mfma_f32_16x16x32_bf16(af, bf, acc[cb], 0, 0, 0);
        }
    }

    const int orow = kq * 4;
#pragma unroll
    for (int cb = 0; cb < NCB; ++cb)
#pragma unroll
        for (int r = 0; r < 4; ++r) {
            const long gr = base + orow + r;
            if (gr < N) H[gr * NOUT + cb * 16 + r0] = (__bf16)acc[cb][r];
        }
}

// --------------------------------- gather + bias + ReLU + LayerNorm -------
// D=128 bf16 H: one wave per node, bf16x2 per lane; writes bf16 ln1 out.
__global__ __launch_bounds__(256) void k_gat128(const __bf16* __restrict__ H,
                                                const int* __restrict__ off,
                                                const int* __restrict__ cnt,
                                                const float2* __restrict__ ern,
                                                const float* __restrict__ dinv,
                                                const float* __restrict__ bias,
                                                const float* __restrict__ gm,
                                                const float* __restrict__ bt,
                                                __bf16* __restrict__ Out, int N) {
    const long wv = ((long)blockIdx.x * 256 + threadIdx.x) >> 6;
    const int lane = threadIdx.x & 63;
    if (wv >= N) return;
    const int s = off[wv];
    const int n = cnt[wv];
    const float d = dinv[wv];
    const bf16x2* Hp = reinterpret_cast<const bf16x2*>(H);

    const bf16x2 h0 = Hp[wv * 64 + lane];
    float ax = (float)h0[0] * d * d, ay = (float)h0[1] * d * d;

    int e = 0;
    for (; e + 8 <= n; e += 8) {
        float2 q[8];
#pragma unroll
        for (int j = 0; j < 8; ++j) q[j] = ern[s + e + j];
        bf16x2 v[8];
#pragma unroll
        for (int j = 0; j < 8; ++j)
            v[j] = Hp[(long)__float_as_int(q[j].x) * 64 + lane];
#pragma unroll
        for (int j = 0; j < 8; ++j) {
            ax = fmaf(q[j].y, (float)v[j][0], ax);
            ay = fmaf(q[j].y, (float)v[j][1], ay);
        }
    }
    for (; e < n; ++e) {
        const float2 q = ern[s + e];
        const bf16x2 v = Hp[(long)__float_as_int(q.x) * 64 + lane];
        ax = fmaf(q.y, (float)v[0], ax);
        ay = fmaf(q.y, (float)v[1], ay);
    }

    const float ux = fmaxf(ax + bias[2 * lane], 0.f);
    const float uy = fmaxf(ay + bias[2 * lane + 1], 0.f);
    float s1 = ux + uy, s2 = ux * ux + uy * uy;
#pragma unroll
    for (int o = 32; o >= 1; o >>= 1) {
        s1 += __shfl_xor(s1, o);
        s2 += __shfl_xor(s2, o);
    }
    const float mu = s1 * (1.f / 128.f);
    const float var = s2 * (1.f / 128.f) - mu * mu;
    const float rs = rsqrtf(var + EPSV);
    bf16x2 ob;
    ob[0] = (__bf16)((ux - mu) * rs * gm[2 * lane] + bt[2 * lane]);
    ob[1] = (__bf16)((uy - mu) * rs * gm[2 * lane + 1] + bt[2 * lane + 1]);
    reinterpret_cast<bf16x2*>(Out)[wv * 64 + lane] = ob;
}

// D=64 bf16 H: one wave per node; writes fp32 LN output (pool input).
__global__ __launch_bounds__(256) void k_gat64(const __bf16* __restrict__ H,
                                               const int* __restrict__ off,
                                               const int* __restrict__ cnt,
                                               const float2* __restrict__ ern,
                                               const float* __restrict__ dinv,
                                               const float* __restrict__ bias,
                                               const float* __restrict__ gm,
                                               const float* __restrict__ bt,
                                               float* __restrict__ Out, int N) {
    const long wv = ((long)blockIdx.x * 256 + threadIdx.x) >> 6;
    const int lane = threadIdx.x & 63;
    if (wv >= N) return;
    const int s = off[wv];
    const int n = cnt[wv];
    const float d = dinv[wv];

    float acc = (float)H[wv * 64 + lane] * d * d;
    int e = 0;
    for (; e + 8 <= n; e += 8) {
        float2 q[8];
#pragma unroll
        for (int j = 0; j < 8; ++j) q[j] = ern[s + e + j];
        float v[8];
#pragma unroll
        for (int j = 0; j < 8; ++j)
            v[j] = (float)H[(long)__float_as_int(q[j].x) * 64 + lane];
#pragma unroll
        for (int j = 0; j < 8; ++j) acc = fmaf(q[j].y, v[j], acc);
    }
    for (; e < n; ++e) {
        const float2 q = ern[s + e];
        acc = fmaf(q.y, (float)H[(long)__float_as_int(q.x) * 64 + lane], acc);
    }

    const float u = fmaxf(acc + bias[lane], 0.f);
    float s1 = u, s2 = u * u;
#pragma unroll
    for (int o = 32; o >= 1; o >>= 1) {
        s1 += __shfl_xor(s1, o);
        s2 += __shfl_xor(s2, o);
    }
    const float mu = s1 * (1.f / 64.f);
    const float var = s2 * (1.f / 64.f) - mu * mu;
    const float rs = rsqrtf(var + EPSV);
    Out[wv * 64 + lane] = (u - mu) * rs * gm[lane] + bt[lane];
}

// ---------------------------------------------------------------- pool ----
__global__ __launch_bounds__(256) void k_pool(const float* __restrict__ C,
                                              const int* __restrict__ batch,
                                              float* __restrict__ pool,
                                              int N, int chunk) {
    const int wg = blockIdx.x * 4 + (threadIdx.x >> 6);
    const int lane = threadIdx.x & 63;
    long i = (long)wg * chunk;
    const long end = (i + chunk < (long)N) ? i + chunk : (long)N;
    if (i >= end) return;

    int cur = batch[i];
    float acc = 0.f;
    int cn = 0;
    while (i < end) {
        if (i + 8 <= end && batch[i + 7] == cur) {
            float v[8];
#pragma unroll
            for (int j = 0; j < 8; ++j) v[j] = C[(i + j) * 64 + lane];
            acc += ((v[0] + v[1]) + (v[2] + v[3])) + ((v[4] + v[5]) + (v[6] + v[7]));
            cn += 8;
            i += 8;
            continue;
        }
        const int b = batch[i];
        if (b != cur) {
            unsafeAtomicAdd(&pool[cur * 64 + lane], acc);
            if (lane == 0) unsafeAtomicAdd(&pool[64 * 64 + cur], (float)cn);
            cur = b;
            acc = 0.f;
            cn = 0;
        }
        acc += C[i * 64 + lane];
        ++cn;
        ++i;
    }
    unsafeAtomicAdd(&pool[cur * 64 + lane], acc);
    if (lane == 0) unsafeAtomicAdd(&pool[64 * 64 + cur], (float)cn);
}

__global__ __launch_bounds__(256) void k_final(const float* __restrict__ pool,
                                               float* __restrict__ out) {
    const int i = blockIdx.x * 256 + threadIdx.x;
    if (i < 4096) {
        const int g = i >> 6;
        const float cnt = fmaxf(pool[64 * 64 + g], 1.0f);
        const float v = pool[i] / cnt;
        out[i] = 1.f / (1.f + expf(-v));
    }
}

// -------------------------------------------------------------- launch ----
extern "C" void kernel_launch(void* const* d_in, const int* in_sizes, int n_in,
                              void* d_out, int out_size, void* d_ws, size_t ws_size,
                              hipStream_t stream) {
    const float* x   = (const float*)d_in[0];
    const int*   ei  = (const int*)d_in[1];
    const float* ew  = (const float*)d_in[2];
    const int*   bat = (const int*)d_in[3];
    const float* W1  = (const float*)d_in[4];
    const float* b1  = (const float*)d_in[5];
    const float* g1  = (const float*)d_in[6];
    const float* bt1 = (const float*)d_in[7];
    const float* W2  = (const float*)d_in[8];
    const float* b2  = (const float*)d_in[9];
    const float* g2  = (const float*)d_in[10];
    const float* bt2 = (const float*)d_in[11];
    const int N = in_sizes[3];
    const int E = in_sizes[2];
    const int NB = (N + 255) / 256;

    // layout (16B-aligned chunks): dc | pool | ern | Ah | Bh | Cf | dinv | cnt | off | bsum | rank | Wt1 | Wt2
    u64*    dc   = (u64*)d_ws;                         // [N] packed deg/cnt
    float*  pool = (float*)(dc + N);                   // [64*64+64]
    float2* ern  = (float2*)(pool + 64 * 64 + 64);     // [E]
    __bf16* Ah   = (__bf16*)(ern + E);                 // [N*128] h1; reused h2 [N*64]
    __bf16* Bh   = Ah + (long)N * 128;                 // [N*128] ln1 out
    float*  Cf   = (float*)(Bh + (long)N * 128);       // [N*64] ln2 out
    float*  dinv = Cf + (long)N * 64;                  // [N]
    int*    cnt  = (int*)(dinv + N);                   // [N]
    int*    off  = cnt + N;                            // [N]
    int*    bsum = off + N;                            // [NB] (padded)
    unsigned short* rank = (unsigned short*)(bsum + ((NB + 3) & ~3)); // [E]
    __bf16* Wt1  = (__bf16*)(rank + E);                // [128*256]
    __bf16* Wt2  = Wt1 + 128 * 256;                    // [64*128]

    const int nbE = (E + 255) / 256;
    const int nbW = (int)(((long)N * 64 + 255) / 256);

    hipMemsetAsync(dc, 0, (size_t)N * 8 + (64 * 64 + 64) * 4, stream);
    k_degacc<<<nbE, 256, 0, stream>>>(ei, ew, dc, rank, E);
    k_scanA<<<NB, 256, 0, stream>>>(dc, dinv, cnt, bsum, N);
    k_scan2<<<1, 256, 0, stream>>>(bsum, NB);
    k_scan3<<<NB, 256, 0, stream>>>(cnt, bsum, off, N);
    k_fill<<<nbE, 256, 0, stream>>>(ei, ew, dinv, off, rank, ern, E);
    k_wcvt<<<(128 * 256 + 64 * 128 + 255) / 256, 256, 0, stream>>>(W1, Wt1, W2, Wt2);

    // layer 1: GCNConv(256->128) + ReLU + LN
    k_mm<256, 128, false><<<(N + 63) / 64, 256, 0, stream>>>(x, Wt1, Ah, N);
    k_gat128<<<nbW, 256, 0, stream>>>(Ah, off, cnt, ern, dinv, b1, g1, bt1, Bh, N);

    // layer 2: GCNConv(128->64) + ReLU + LN
    k_mm<128, 64, true><<<(N + 63) / 64, 256, 0, stream>>>(Bh, Wt2, Ah, N);
    k_gat64<<<nbW, 256, 0, stream>>>(Ah, off, cnt, ern, dinv, b2, g2, bt2, Cf, N);

    // global mean pool + sigmoid
    const int chunk = (N + 1023) / 1024;
    k_pool<<<256, 256, 0, stream>>>(Cf, bat, pool, N, chunk);
    k_final<<<16, 256, 0, stream>>>(pool, (float*)d_out);
}

// Round 6
// 337.105 us; speedup vs baseline: 14.9782x; 1.1283x over previous
//
#include <hip/hip_runtime.h>
#include <cstdint>

#define EPSV 1e-5f

typedef __bf16 bf16x8 __attribute__((ext_vector_type(8)));
typedef __bf16 bf16x2 __attribute__((ext_vector_type(2)));
typedef float  f32x4  __attribute__((ext_vector_type(4)));
typedef unsigned long long u64;

// ------------------------------------------------- deg/cnt/rank in one ----
// dc[c] += (1<<40) | fix24(w); old>>40 = this edge's within-node rank.
__global__ __launch_bounds__(256) void k_degacc(const int* __restrict__ ei,
                                                const float* __restrict__ ew,
                                                u64* __restrict__ dc,
                                                unsigned short* __restrict__ rank,
                                                int E) {
    const int e = blockIdx.x * 256 + threadIdx.x;
    if (e < E) {
        const int c = ei[E + e];
        const u64 pack = (1ull << 40) | (u64)(ew[e] * 16777216.0f);
        const u64 old = atomicAdd(&dc[c], pack);
        rank[e] = (unsigned short)(old >> 40);
    }
}

// ------------------------------- unpack: dinv + cnt + block-sum (scan1) ---
__global__ __launch_bounds__(256) void k_scanA(const u64* __restrict__ dc,
                                               float* __restrict__ dinv,
                                               int* __restrict__ cnt,
                                               int* __restrict__ bsum, int N) {
    __shared__ int ws[4];
    const int i = blockIdx.x * 256 + threadIdx.x;
    int v = 0;
    if (i < N) {
        const u64 p = dc[i];
        v = (int)(p >> 40);
        const float deg = 1.0f + (float)(p & 0xFFFFFFFFFFull) * (1.0f / 16777216.0f);
        dinv[i] = rsqrtf(deg);  // deg >= 1 always (self loop)
        cnt[i] = v;
    }
#pragma unroll
    for (int o = 32; o >= 1; o >>= 1) v += __shfl_xor(v, o);
    if ((threadIdx.x & 63) == 0) ws[threadIdx.x >> 6] = v;
    __syncthreads();
    if (threadIdx.x == 0) bsum[blockIdx.x] = ws[0] + ws[1] + ws[2] + ws[3];
}

__global__ __launch_bounds__(256) void k_scan2(int* __restrict__ bsum, int NB) {
    __shared__ int carry;
    __shared__ int wsum[4];
    if (threadIdx.x == 0) carry = 0;
    __syncthreads();
    const int lane = threadIdx.x & 63, w = threadIdx.x >> 6;
    for (int base = 0; base < NB; base += 256) {
        const int i = base + threadIdx.x;
        const int v = (i < NB) ? bsum[i] : 0;
        int s = v;
#pragma unroll
        for (int o = 1; o < 64; o <<= 1) {
            const int t = __shfl_up(s, o);
            if (lane >= o) s += t;
        }
        if (lane == 63) wsum[w] = s;
        __syncthreads();
        int add = carry;
        for (int k = 0; k < w; ++k) add += wsum[k];
        const int tot = wsum[0] + wsum[1] + wsum[2] + wsum[3];
        if (i < NB) bsum[i] = add + s - v;
        __syncthreads();
        if (threadIdx.x == 0) carry += tot;
        __syncthreads();
    }
}

__global__ __launch_bounds__(256) void k_scan3(const int* __restrict__ cnt,
                                               const int* __restrict__ bsum,
                                               int* __restrict__ off, int N) {
    __shared__ int wsum[4];
    const int i = blockIdx.x * 256 + threadIdx.x;
    const int v = (i < N) ? cnt[i] : 0;
    const int lane = threadIdx.x & 63, w = threadIdx.x >> 6;
    int s = v;
#pragma unroll
    for (int o = 1; o < 64; o <<= 1) {
        const int t = __shfl_up(s, o);
        if (lane >= o) s += t;
    }
    if (lane == 63) wsum[w] = s;
    __syncthreads();
    int add = bsum[blockIdx.x];
    for (int k = 0; k < w; ++k) add += wsum[k];
    if (i < N) off[i] = add + s - v;
}

// ------------------- CSR fill, atomic-free: slot = off[c] + rank[e] -------
__global__ __launch_bounds__(256) void k_fill(const int* __restrict__ ei,
                                              const float* __restrict__ ew,
                                              const float* __restrict__ dinv,
                                              const int* __restrict__ off,
                                              const unsigned short* __restrict__ rank,
                                              float2* __restrict__ ern, int E) {
    const int e = blockIdx.x * 256 + threadIdx.x;
    if (e >= E) return;
    const int r = ei[e];
    const int c = ei[E + e];
    const int p = off[c] + (int)rank[e];
    ern[p] = make_float2(__int_as_float(r), dinv[r] * ew[e] * dinv[c]);
}

// ----------------------------------------------------- W transpose+cvt ----
// Blob layout: WtB[k/8][c][8] bf16, i.e. elem = ((k>>3)*NOUT + c)*8 + (k&7).
// A wave's B-fragment read (16 rows, same k-chunk) is then 256B contiguous.
__global__ __launch_bounds__(256) void k_wcvt(const float* __restrict__ W1,
                                              __bf16* __restrict__ Wt1,
                                              const float* __restrict__ W2,
                                              __bf16* __restrict__ Wt2) {
    const int idx = blockIdx.x * 256 + threadIdx.x;
    if (idx < 256 * 128) {                       // K=256, NOUT=128
        const int k = idx >> 7, c = idx & 127;
        Wt1[(((k >> 3) << 7) + c) * 8 + (k & 7)] = (__bf16)W1[idx];
    } else if (idx < 256 * 128 + 128 * 64) {     // K=128, NOUT=64
        const int j = idx - 256 * 128;
        const int k = j >> 6, c = j & 63;
        Wt2[(((k >> 3) << 6) + c) * 8 + (k & 7)] = (__bf16)W2[j];
    }
}

// ----------------------------------------------------------- MFMA GEMM ----
// H[N][NOUT] = X[N][K] @ W -> bf16. WtB is blob layout (see k_wcvt).
// 4 waves x 32 rows = 128-row block tile; 2 row-fragments per wave.
// Manual 2-stage pipeline: next K-step's A+B loads issued before MFMAs.
template <int K, int NOUT, bool ABF16>
__global__ __launch_bounds__(256) void k_mm(const void* __restrict__ Xv,
                                            const __bf16* __restrict__ WtB,
                                            __bf16* __restrict__ H, int N) {
    constexpr int NCB = NOUT / 16;
    constexpr int NKB = K / 32;
    const int tid = threadIdx.x;
    const int w = tid >> 6, l = tid & 63;
    const int r0 = l & 15, kq = l >> 4;
    const long tb0 = (long)blockIdx.x * 128 + w * 32;       // rf=0 tile base
    const long ar0 = (tb0 + r0) < N ? (tb0 + r0) : (long)N - 1;
    const long ar1 = (tb0 + 16 + r0) < N ? (tb0 + 16 + r0) : (long)N - 1;

    f32x4 acc[2][NCB];
#pragma unroll
    for (int rf = 0; rf < 2; ++rf)
#pragma unroll
        for (int cb = 0; cb < NCB; ++cb) acc[rf][cb] = (f32x4){0.f, 0.f, 0.f, 0.f};

#define LDA(kb, a0, a1)                                                          \
    {                                                                            \
        const int koff = (kb) * 32 + kq * 8;                                     \
        if constexpr (ABF16) {                                                   \
            a0 = *reinterpret_cast<const bf16x8*>((const __bf16*)Xv + ar0 * K + koff); \
            a1 = *reinterpret_cast<const bf16x8*>((const __bf16*)Xv + ar1 * K + koff); \
        } else {                                                                 \
            const float* p0 = (const float*)Xv + ar0 * K + koff;                 \
            const float* p1 = (const float*)Xv + ar1 * K + koff;                 \
            const float4 u0 = *reinterpret_cast<const float4*>(p0);              \
            const float4 u1 = *reinterpret_cast<const float4*>(p0 + 4);          \
            const float4 u2 = *reinterpret_cast<const float4*>(p1);              \
            const float4 u3 = *reinterpret_cast<const float4*>(p1 + 4);          \
            a0[0] = (__bf16)u0.x; a0[1] = (__bf16)u0.y; a0[2] = (__bf16)u0.z;    \
            a0[3] = (__bf16)u0.w; a0[4] = (__bf16)u1.x; a0[5] = (__bf16)u1.y;    \
            a0[6] = (__bf16)u1.z; a0[7] = (__bf16)u1.w;                          \
            a1[0] = (__bf16)u2.x; a1[1] = (__bf16)u2.y; a1[2] = (__bf16)u2.z;    \
            a1[3] = (__bf16)u2.w; a1[4] = (__bf16)u3.x; a1[5] = (__bf16)u3.y;    \
            a1[6] = (__bf16)u3.z; a1[7] = (__bf16)u3.w;                          \
        }                                                                        \
    }

#define LDB(kb, b)                                                               \
    {                                                                            \
        const __bf16* bp = WtB + (long)(((kb) * 4 + kq) * NOUT + r0) * 8;        \
        _Pragma("unroll") for (int cb = 0; cb < NCB; ++cb)                       \
            b[cb] = *reinterpret_cast<const bf16x8*>(bp + cb * 128);             \
    }

    bf16x8 aC0, aC1, aN0, aN1;
    bf16x8 bC[NCB], bN[NCB];
    LDA(0, aC0, aC1);
    LDB(0, bC);
#pragma unroll
    for (int kb = 0; kb < NKB; ++kb) {
        if (kb + 1 < NKB) {
            LDA(kb + 1, aN0, aN1);
            LDB(kb + 1, bN);
        }
#pragma unroll
        for (int cb = 0; cb < NCB; ++cb) {
            acc[0][cb] = __builtin_amdgcn_mfma_f32_16x16x32_bf16(aC0, bC[cb], acc[0][cb], 0, 0, 0);
            acc[1][cb] = __builtin_amdgcn_mfma_f32_16x16x32_bf16(aC1, bC[cb], acc[1][cb], 0, 0, 0);
        }
        aC0 = aN0; aC1 = aN1;
#pragma unroll
        for (int cb = 0; cb < NCB; ++cb) bC[cb] = bN[cb];
    }
#undef LDA
#undef LDB

    const int orow = kq * 4;
#pragma unroll
    for (int rf = 0; rf < 2; ++rf)
#pragma unroll
        for (int cb = 0; cb < NCB; ++cb)
#pragma unroll
            for (int r = 0; r < 4; ++r) {
                const long gr = tb0 + rf * 16 + orow + r;
                if (gr < N) H[gr * NOUT + cb * 16 + r0] = (__bf16)acc[rf][cb][r];
            }
}

// --------------------------------- gather + bias + ReLU + LayerNorm -------
// D=128 bf16 H: one wave per node, bf16x2 per lane; writes bf16 ln1 out.
__global__ __launch_bounds__(256) void k_gat128(const __bf16* __restrict__ H,
                                                const int* __restrict__ off,
                                                const int* __restrict__ cnt,
                                                const float2* __restrict__ ern,
                                                const float* __restrict__ dinv,
                                                const float* __restrict__ bias,
                                                const float* __restrict__ gm,
                                                const float* __restrict__ bt,
                                                __bf16* __restrict__ Out, int N) {
    const long wv = ((long)blockIdx.x * 256 + threadIdx.x) >> 6;
    const int lane = threadIdx.x & 63;
    if (wv >= N) return;
    const int s = off[wv];
    const int n = cnt[wv];
    const float d = dinv[wv];
    const bf16x2* Hp = reinterpret_cast<const bf16x2*>(H);

    const bf16x2 h0 = Hp[wv * 64 + lane];
    float ax = (float)h0[0] * d * d, ay = (float)h0[1] * d * d;

    int e = 0;
    for (; e + 8 <= n; e += 8) {
        float2 q[8];
#pragma unroll
        for (int j = 0; j < 8; ++j) q[j] = ern[s + e + j];
        bf16x2 v[8];
#pragma unroll
        for (int j = 0; j < 8; ++j)
            v[j] = Hp[(long)__float_as_int(q[j].x) * 64 + lane];
#pragma unroll
        for (int j = 0; j < 8; ++j) {
            ax = fmaf(q[j].y, (float)v[j][0], ax);
            ay = fmaf(q[j].y, (float)v[j][1], ay);
        }
    }
    for (; e < n; ++e) {
        const float2 q = ern[s + e];
        const bf16x2 v = Hp[(long)__float_as_int(q.x) * 64 + lane];
        ax = fmaf(q.y, (float)v[0], ax);
        ay = fmaf(q.y, (float)v[1], ay);
    }

    const float ux = fmaxf(ax + bias[2 * lane], 0.f);
    const float uy = fmaxf(ay + bias[2 * lane + 1], 0.f);
    float s1 = ux + uy, s2 = ux * ux + uy * uy;
#pragma unroll
    for (int o = 32; o >= 1; o >>= 1) {
        s1 += __shfl_xor(s1, o);
        s2 += __shfl_xor(s2, o);
    }
    const float mu = s1 * (1.f / 128.f);
    const float var = s2 * (1.f / 128.f) - mu * mu;
    const float rs = rsqrtf(var + EPSV);
    bf16x2 ob;
    ob[0] = (__bf16)((ux - mu) * rs * gm[2 * lane] + bt[2 * lane]);
    ob[1] = (__bf16)((uy - mu) * rs * gm[2 * lane + 1] + bt[2 * lane + 1]);
    reinterpret_cast<bf16x2*>(Out)[wv * 64 + lane] = ob;
}

// D=64 bf16 H: one wave per node; writes fp32 LN output (pool input).
__global__ __launch_bounds__(256) void k_gat64(const __bf16* __restrict__ H,
                                               const int* __restrict__ off,
                                               const int* __restrict__ cnt,
                                               const float2* __restrict__ ern,
                                               const float* __restrict__ dinv,
                                               const float* __restrict__ bias,
                                               const float* __restrict__ gm,
                                               const float* __restrict__ bt,
                                               float* __restrict__ Out, int N) {
    const long wv = ((long)blockIdx.x * 256 + threadIdx.x) >> 6;
    const int lane = threadIdx.x & 63;
    if (wv >= N) return;
    const int s = off[wv];
    const int n = cnt[wv];
    const float d = dinv[wv];

    float acc = (float)H[wv * 64 + lane] * d * d;
    int e = 0;
    for (; e + 8 <= n; e += 8) {
        float2 q[8];
#pragma unroll
        for (int j = 0; j < 8; ++j) q[j] = ern[s + e + j];
        float v[8];
#pragma unroll
        for (int j = 0; j < 8; ++j)
            v[j] = (float)H[(long)__float_as_int(q[j].x) * 64 + lane];
#pragma unroll
        for (int j = 0; j < 8; ++j) acc = fmaf(q[j].y, v[j], acc);
    }
    for (; e < n; ++e) {
        const float2 q = ern[s + e];
        acc = fmaf(q.y, (float)H[(long)__float_as_int(q.x) * 64 + lane], acc);
    }

    const float u = fmaxf(acc + bias[lane], 0.f);
    float s1 = u, s2 = u * u;
#pragma unroll
    for (int o = 32; o >= 1; o >>= 1) {
        s1 += __shfl_xor(s1, o);
        s2 += __shfl_xor(s2, o);
    }
    const float mu = s1 * (1.f / 64.f);
    const float var = s2 * (1.f / 64.f) - mu * mu;
    const float rs = rsqrtf(var + EPSV);
    Out[wv * 64 + lane] = (u - mu) * rs * gm[lane] + bt[lane];
}

// ---------------------------------------------------------------- pool ----
__global__ __launch_bounds__(256) void k_pool(const float* __restrict__ C,
                                              const int* __restrict__ batch,
                                              float* __restrict__ pool,
                                              int N, int chunk) {
    const int wg = blockIdx.x * 4 + (threadIdx.x >> 6);
    const int lane = threadIdx.x & 63;
    long i = (long)wg * chunk;
    const long end = (i + chunk < (long)N) ? i + chunk : (long)N;
    if (i >= end) return;

    int cur = batch[i];
    float acc = 0.f;
    int cn = 0;
    while (i < end) {
        if (i + 8 <= end && batch[i + 7] == cur) {
            float v[8];
#pragma unroll
            for (int j = 0; j < 8; ++j) v[j] = C[(i + j) * 64 + lane];
            acc += ((v[0] + v[1]) + (v[2] + v[3])) + ((v[4] + v[5]) + (v[6] + v[7]));
            cn += 8;
            i += 8;
            continue;
        }
        const int b = batch[i];
        if (b != cur) {
            unsafeAtomicAdd(&pool[cur * 64 + lane], acc);
            if (lane == 0) unsafeAtomicAdd(&pool[64 * 64 + cur], (float)cn);
            cur = b;
            acc = 0.f;
            cn = 0;
        }
        acc += C[i * 64 + lane];
        ++cn;
        ++i;
    }
    unsafeAtomicAdd(&pool[cur * 64 + lane], acc);
    if (lane == 0) unsafeAtomicAdd(&pool[64 * 64 + cur], (float)cn);
}

__global__ __launch_bounds__(256) void k_final(const float* __restrict__ pool,
                                               float* __restrict__ out) {
    const int i = blockIdx.x * 256 + threadIdx.x;
    if (i < 4096) {
        const int g = i >> 6;
        const float cnt = fmaxf(pool[64 * 64 + g], 1.0f);
        const float v = pool[i] / cnt;
        out[i] = 1.f / (1.f + expf(-v));
    }
}

// -------------------------------------------------------------- launch ----
extern "C" void kernel_launch(void* const* d_in, const int* in_sizes, int n_in,
                              void* d_out, int out_size, void* d_ws, size_t ws_size,
                              hipStream_t stream) {
    const float* x   = (const float*)d_in[0];
    const int*   ei  = (const int*)d_in[1];
    const float* ew  = (const float*)d_in[2];
    const int*   bat = (const int*)d_in[3];
    const float* W1  = (const float*)d_in[4];
    const float* b1  = (const float*)d_in[5];
    const float* g1  = (const float*)d_in[6];
    const float* bt1 = (const float*)d_in[7];
    const float* W2  = (const float*)d_in[8];
    const float* b2  = (const float*)d_in[9];
    const float* g2  = (const float*)d_in[10];
    const float* bt2 = (const float*)d_in[11];
    const int N = in_sizes[3];
    const int E = in_sizes[2];
    const int NB = (N + 255) / 256;

    u64*    dc   = (u64*)d_ws;                         // [N] packed deg/cnt
    float*  pool = (float*)(dc + N);                   // [64*64+64]
    float2* ern  = (float2*)(pool + 64 * 64 + 64);     // [E]
    __bf16* Ah   = (__bf16*)(ern + E);                 // [N*128] h1; reused h2 [N*64]
    __bf16* Bh   = Ah + (long)N * 128;                 // [N*128] ln1 out
    float*  Cf   = (float*)(Bh + (long)N * 128);       // [N*64] ln2 out
    float*  dinv = Cf + (long)N * 64;                  // [N]
    int*    cnt  = (int*)(dinv + N);                   // [N]
    int*    off  = cnt + N;                            // [N]
    int*    bsum = off + N;                            // [NB] (padded)
    unsigned short* rank = (unsigned short*)(bsum + ((NB + 3) & ~3)); // [E]
    __bf16* Wt1  = (__bf16*)(rank + E);                // [128*256] blob layout
    __bf16* Wt2  = Wt1 + 128 * 256;                    // [64*128] blob layout

    const int nbE = (E + 255) / 256;
    const int nbW = (int)(((long)N * 64 + 255) / 256);

    hipMemsetAsync(dc, 0, (size_t)N * 8 + (64 * 64 + 64) * 4, stream);
    k_degacc<<<nbE, 256, 0, stream>>>(ei, ew, dc, rank, E);
    k_scanA<<<NB, 256, 0, stream>>>(dc, dinv, cnt, bsum, N);
    k_scan2<<<1, 256, 0, stream>>>(bsum, NB);
    k_scan3<<<NB, 256, 0, stream>>>(cnt, bsum, off, N);
    k_fill<<<nbE, 256, 0, stream>>>(ei, ew, dinv, off, rank, ern, E);
    k_wcvt<<<(256 * 128 + 128 * 64 + 255) / 256, 256, 0, stream>>>(W1, Wt1, W2, Wt2);

    // layer 1: GCNConv(256->128) + ReLU + LN
    k_mm<256, 128, false><<<(N + 127) / 128, 256, 0, stream>>>(x, Wt1, Ah, N);
    k_gat128<<<nbW, 256, 0, stream>>>(Ah, off, cnt, ern, dinv, b1, g1, bt1, Bh, N);

    // layer 2: GCNConv(128->64) + ReLU + LN
    k_mm<128, 64, true><<<(N + 127) / 128, 256, 0, stream>>>(Bh, Wt2, Ah, N);
    k_gat64<<<nbW, 256, 0, stream>>>(Ah, off, cnt, ern, dinv, b2, g2, bt2, Cf, N);

    // global mean pool + sigmoid
    const int chunk = (N + 1023) / 1024;
    k_pool<<<256, 256, 0, stream>>>(Cf, bat, pool, N, chunk);
    k_final<<<16, 256, 0, stream>>>(pool, (float*)d_out);
}

// Round 7
// 317.852 us; speedup vs baseline: 15.8855x; 1.0606x over previous
//
#include <hip/hip_runtime.h>
#include <cstdint>

#define EPSV 1e-5f

typedef __bf16 bf16x8 __attribute__((ext_vector_type(8)));
typedef __bf16 bf16x2 __attribute__((ext_vector_type(2)));
typedef float  f32x4  __attribute__((ext_vector_type(4)));
typedef unsigned long long u64;

// fp8 e4m3 (OCP) helpers — HW converts on gfx950.
__device__ __forceinline__ unsigned char f32_to_fp8(float x) {
    const int p = __builtin_amdgcn_cvt_pk_fp8_f32(x, x, 0, false);
    return (unsigned char)(p & 0xFF);
}

// ------------------------------------------------------- prefix scan ------
__global__ __launch_bounds__(256) void k_scanA(const u64* __restrict__ dc,
                                               float* __restrict__ dinv,
                                               int* __restrict__ cnt,
                                               int* __restrict__ bsum, int N) {
    __shared__ int ws[4];
    const int i = blockIdx.x * 256 + threadIdx.x;
    int v = 0;
    if (i < N) {
        const u64 p = dc[i];
        v = (int)(p >> 40);
        const float deg = 1.0f + (float)(p & 0xFFFFFFFFFFull) * (1.0f / 16777216.0f);
        dinv[i] = rsqrtf(deg);  // deg >= 1 always (self loop)
        cnt[i] = v;
    }
#pragma unroll
    for (int o = 32; o >= 1; o >>= 1) v += __shfl_xor(v, o);
    if ((threadIdx.x & 63) == 0) ws[threadIdx.x >> 6] = v;
    __syncthreads();
    if (threadIdx.x == 0) bsum[blockIdx.x] = ws[0] + ws[1] + ws[2] + ws[3];
}

__global__ __launch_bounds__(256) void k_scan2(int* __restrict__ bsum, int NB) {
    __shared__ int carry;
    __shared__ int wsum[4];
    if (threadIdx.x == 0) carry = 0;
    __syncthreads();
    const int lane = threadIdx.x & 63, w = threadIdx.x >> 6;
    for (int base = 0; base < NB; base += 256) {
        const int i = base + threadIdx.x;
        const int v = (i < NB) ? bsum[i] : 0;
        int s = v;
#pragma unroll
        for (int o = 1; o < 64; o <<= 1) {
            const int t = __shfl_up(s, o);
            if (lane >= o) s += t;
        }
        if (lane == 63) wsum[w] = s;
        __syncthreads();
        int add = carry;
        for (int k = 0; k < w; ++k) add += wsum[k];
        const int tot = wsum[0] + wsum[1] + wsum[2] + wsum[3];
        if (i < NB) bsum[i] = add + s - v;
        __syncthreads();
        if (threadIdx.x == 0) carry += tot;
        __syncthreads();
    }
}

__global__ __launch_bounds__(256) void k_scan3(const int* __restrict__ cnt,
                                               const int* __restrict__ bsum,
                                               int* __restrict__ off, int N) {
    __shared__ int wsum[4];
    const int i = blockIdx.x * 256 + threadIdx.x;
    const int v = (i < N) ? cnt[i] : 0;
    const int lane = threadIdx.x & 63, w = threadIdx.x >> 6;
    int s = v;
#pragma unroll
    for (int o = 1; o < 64; o <<= 1) {
        const int t = __shfl_up(s, o);
        if (lane >= o) s += t;
    }
    if (lane == 63) wsum[w] = s;
    __syncthreads();
    int add = bsum[blockIdx.x];
    for (int k = 0; k < w; ++k) add += wsum[k];
    if (i < N) off[i] = add + s - v;
}

// ------------------- CSR fill, atomic-free: slot = off[c] + rank[e] -------
__global__ __launch_bounds__(256) void k_fill(const int* __restrict__ ei,
                                              const float* __restrict__ ew,
                                              const float* __restrict__ dinv,
                                              const int* __restrict__ off,
                                              const unsigned short* __restrict__ rank,
                                              float2* __restrict__ ern, int E) {
    const int e = blockIdx.x * 256 + threadIdx.x;
    if (e >= E) return;
    const int r = ei[e];
    const int c = ei[E + e];
    const int p = off[c] + (int)rank[e];
    ern[p] = make_float2(__int_as_float(r), dinv[r] * ew[e] * dinv[c]);
}

// ----------------------------------------------------- W transpose+cvt ----
// Blob layout: WtB[k/8][c][8] bf16, i.e. elem = ((k>>3)*NOUT + c)*8 + (k&7).
__global__ __launch_bounds__(256) void k_wcvt(const float* __restrict__ W1,
                                              __bf16* __restrict__ Wt1,
                                              const float* __restrict__ W2,
                                              __bf16* __restrict__ Wt2) {
    const int idx = blockIdx.x * 256 + threadIdx.x;
    if (idx < 256 * 128) {                       // K=256, NOUT=128
        const int k = idx >> 7, c = idx & 127;
        Wt1[(((k >> 3) << 7) + c) * 8 + (k & 7)] = (__bf16)W1[idx];
    } else if (idx < 256 * 128 + 128 * 64) {     // K=128, NOUT=64
        const int j = idx - 256 * 128;
        const int k = j >> 6, c = j & 63;
        Wt2[(((k >> 3) << 6) + c) * 8 + (k & 7)] = (__bf16)W2[j];
    }
}

// ----------------------------------------------------------- MFMA GEMM ----
// H[N][NOUT] = X[N][K] @ W -> fp8 e4m3. WtB is blob layout (see k_wcvt).
// 4 waves x 32 rows = 128-row block tile; 2 row-fragments per wave.
// Manual 2-stage pipeline: next K-step's A+B loads issued before MFMAs.
template <int K, int NOUT, bool ABF16>
__device__ __forceinline__ void mm_body(int bid, int tid, const void* __restrict__ Xv,
                                        const __bf16* __restrict__ WtB,
                                        unsigned char* __restrict__ H, int N) {
    constexpr int NCB = NOUT / 16;
    constexpr int NKB = K / 32;
    const int w = tid >> 6, l = tid & 63;
    const int r0 = l & 15, kq = l >> 4;
    const long tb0 = (long)bid * 128 + w * 32;
    const long ar0 = (tb0 + r0) < N ? (tb0 + r0) : (long)N - 1;
    const long ar1 = (tb0 + 16 + r0) < N ? (tb0 + 16 + r0) : (long)N - 1;

    f32x4 acc[2][NCB];
#pragma unroll
    for (int rf = 0; rf < 2; ++rf)
#pragma unroll
        for (int cb = 0; cb < NCB; ++cb) acc[rf][cb] = (f32x4){0.f, 0.f, 0.f, 0.f};

#define LDA(kb, a0, a1)                                                          \
    {                                                                            \
        const int koff = (kb) * 32 + kq * 8;                                     \
        if constexpr (ABF16) {                                                   \
            a0 = *reinterpret_cast<const bf16x8*>((const __bf16*)Xv + ar0 * K + koff); \
            a1 = *reinterpret_cast<const bf16x8*>((const __bf16*)Xv + ar1 * K + koff); \
        } else {                                                                 \
            const float* p0 = (const float*)Xv + ar0 * K + koff;                 \
            const float* p1 = (const float*)Xv + ar1 * K + koff;                 \
            const float4 u0 = *reinterpret_cast<const float4*>(p0);              \
            const float4 u1 = *reinterpret_cast<const float4*>(p0 + 4);          \
            const float4 u2 = *reinterpret_cast<const float4*>(p1);              \
            const float4 u3 = *reinterpret_cast<const float4*>(p1 + 4);          \
            a0[0] = (__bf16)u0.x; a0[1] = (__bf16)u0.y; a0[2] = (__bf16)u0.z;    \
            a0[3] = (__bf16)u0.w; a0[4] = (__bf16)u1.x; a0[5] = (__bf16)u1.y;    \
            a0[6] = (__bf16)u1.z; a0[7] = (__bf16)u1.w;                          \
            a1[0] = (__bf16)u2.x; a1[1] = (__bf16)u2.y; a1[2] = (__bf16)u2.z;    \
            a1[3] = (__bf16)u2.w; a1[4] = (__bf16)u3.x; a1[5] = (__bf16)u3.y;    \
            a1[6] = (__bf16)u3.z; a1[7] = (__bf16)u3.w;                          \
        }                                                                        \
    }

#define LDB(kb, b)                                                               \
    {                                                                            \
        const __bf16* bp = WtB + (long)(((kb) * 4 + kq) * NOUT + r0) * 8;        \
        _Pragma("unroll") for (int cb = 0; cb < NCB; ++cb)                       \
            b[cb] = *reinterpret_cast<const bf16x8*>(bp + cb * 128);             \
    }

    bf16x8 aC0, aC1, aN0, aN1;
    bf16x8 bC[NCB], bN[NCB];
    LDA(0, aC0, aC1);
    LDB(0, bC);
#pragma unroll
    for (int kb = 0; kb < NKB; ++kb) {
        if (kb + 1 < NKB) {
            LDA(kb + 1, aN0, aN1);
            LDB(kb + 1, bN);
        }
#pragma unroll
        for (int cb = 0; cb < NCB; ++cb) {
            acc[0][cb] = __builtin_amdgcn_mfma_f32_16x16x32_bf16(aC0, bC[cb], acc[0][cb], 0, 0, 0);
            acc[1][cb] = __builtin_amdgcn_mfma_f32_16x16x32_bf16(aC1, bC[cb], acc[1][cb], 0, 0, 0);
        }
        aC0 = aN0; aC1 = aN1;
#pragma unroll
        for (int cb = 0; cb < NCB; ++cb) bC[cb] = bN[cb];
    }
#undef LDA
#undef LDB

    const int orow = kq * 4;
#pragma unroll
    for (int rf = 0; rf < 2; ++rf)
#pragma unroll
        for (int cb = 0; cb < NCB; ++cb)
#pragma unroll
            for (int r = 0; r < 4; ++r) {
                const long gr = tb0 + rf * 16 + orow + r;
                if (gr < N) H[gr * NOUT + cb * 16 + r0] = f32_to_fp8(acc[rf][cb][r]);
            }
}

// -------------------- fused: gemm1 (blocks < NBM) || degacc (rest) --------
// Independent work: mm is load/MFMA-bound, degacc is atomic-bound.
__global__ __launch_bounds__(256) void k_pre(const float* __restrict__ X,
                                             const __bf16* __restrict__ Wt1,
                                             unsigned char* __restrict__ H1, int N, int NBM,
                                             const int* __restrict__ ei,
                                             const float* __restrict__ ew,
                                             u64* __restrict__ dc,
                                             unsigned short* __restrict__ rank, int E) {
    if ((int)blockIdx.x < NBM) {
        mm_body<256, 128, false>(blockIdx.x, threadIdx.x, X, Wt1, H1, N);
    } else {
        const int e = ((int)blockIdx.x - NBM) * 256 + threadIdx.x;
        if (e < E) {
            const int c = ei[E + e];
            const u64 pack = (1ull << 40) | (u64)(ew[e] * 16777216.0f);
            const u64 old = atomicAdd(&dc[c], pack);
            rank[e] = (unsigned short)(old >> 40);
        }
    }
}

__global__ __launch_bounds__(256) void k_mm2(const __bf16* __restrict__ X,
                                             const __bf16* __restrict__ Wt2,
                                             unsigned char* __restrict__ H, int N) {
    mm_body<128, 64, true>(blockIdx.x, threadIdx.x, X, Wt2, H, N);
}

// --------------------------------- gather + bias + ReLU + LayerNorm -------
// D=128 fp8 H: one wave per node, 2 fp8 per lane; writes bf16 ln1 out.
__global__ __launch_bounds__(256) void k_gat128(const unsigned char* __restrict__ H,
                                                const int* __restrict__ off,
                                                const int* __restrict__ cnt,
                                                const float2* __restrict__ ern,
                                                const float* __restrict__ dinv,
                                                const float* __restrict__ bias,
                                                const float* __restrict__ gm,
                                                const float* __restrict__ bt,
                                                __bf16* __restrict__ Out, int N) {
    const long wv = ((long)blockIdx.x * 256 + threadIdx.x) >> 6;
    const int lane = threadIdx.x & 63;
    if (wv >= N) return;
    const int s = off[wv];
    const int n = cnt[wv];
    const float d = dinv[wv];
    const unsigned short* Hp = reinterpret_cast<const unsigned short*>(H);

    const unsigned int h0 = Hp[wv * 64 + lane];
    float ax = __builtin_amdgcn_cvt_f32_fp8(h0, 0) * d * d;
    float ay = __builtin_amdgcn_cvt_f32_fp8(h0, 1) * d * d;

    int e = 0;
    for (; e + 8 <= n; e += 8) {
        float2 q[8];
#pragma unroll
        for (int j = 0; j < 8; ++j) q[j] = ern[s + e + j];
        unsigned int u[8];
#pragma unroll
        for (int j = 0; j < 8; ++j)
            u[j] = Hp[(long)__float_as_int(q[j].x) * 64 + lane];
#pragma unroll
        for (int j = 0; j < 8; ++j) {
            ax = fmaf(q[j].y, __builtin_amdgcn_cvt_f32_fp8(u[j], 0), ax);
            ay = fmaf(q[j].y, __builtin_amdgcn_cvt_f32_fp8(u[j], 1), ay);
        }
    }
    for (; e < n; ++e) {
        const float2 q = ern[s + e];
        const unsigned int u = Hp[(long)__float_as_int(q.x) * 64 + lane];
        ax = fmaf(q.y, __builtin_amdgcn_cvt_f32_fp8(u, 0), ax);
        ay = fmaf(q.y, __builtin_amdgcn_cvt_f32_fp8(u, 1), ay);
    }

    const float ux = fmaxf(ax + bias[2 * lane], 0.f);
    const float uy = fmaxf(ay + bias[2 * lane + 1], 0.f);
    float s1 = ux + uy, s2 = ux * ux + uy * uy;
#pragma unroll
    for (int o = 32; o >= 1; o >>= 1) {
        s1 += __shfl_xor(s1, o);
        s2 += __shfl_xor(s2, o);
    }
    const float mu = s1 * (1.f / 128.f);
    const float var = s2 * (1.f / 128.f) - mu * mu;
    const float rs = rsqrtf(var + EPSV);
    bf16x2 ob;
    ob[0] = (__bf16)((ux - mu) * rs * gm[2 * lane] + bt[2 * lane]);
    ob[1] = (__bf16)((uy - mu) * rs * gm[2 * lane + 1] + bt[2 * lane + 1]);
    reinterpret_cast<bf16x2*>(Out)[wv * 64 + lane] = ob;
}

// D=64 fp8 H: one wave per node, 1 fp8 per lane; writes fp32 LN output.
__global__ __launch_bounds__(256) void k_gat64(const unsigned char* __restrict__ H,
                                               const int* __restrict__ off,
                                               const int* __restrict__ cnt,
                                               const float2* __restrict__ ern,
                                               const float* __restrict__ dinv,
                                               const float* __restrict__ bias,
                                               const float* __restrict__ gm,
                                               const float* __restrict__ bt,
                                               float* __restrict__ Out, int N) {
    const long wv = ((long)blockIdx.x * 256 + threadIdx.x) >> 6;
    const int lane = threadIdx.x & 63;
    if (wv >= N) return;
    const int s = off[wv];
    const int n = cnt[wv];
    const float d = dinv[wv];

    float acc = __builtin_amdgcn_cvt_f32_fp8((unsigned int)H[wv * 64 + lane], 0) * d * d;
    int e = 0;
    for (; e + 8 <= n; e += 8) {
        float2 q[8];
#pragma unroll
        for (int j = 0; j < 8; ++j) q[j] = ern[s + e + j];
        unsigned int u[8];
#pragma unroll
        for (int j = 0; j < 8; ++j)
            u[j] = H[(long)__float_as_int(q[j].x) * 64 + lane];
#pragma unroll
        for (int j = 0; j < 8; ++j)
            acc = fmaf(q[j].y, __builtin_amdgcn_cvt_f32_fp8(u[j], 0), acc);
    }
    for (; e < n; ++e) {
        const float2 q = ern[s + e];
        const unsigned int u = H[(long)__float_as_int(q.x) * 64 + lane];
        acc = fmaf(q.y, __builtin_amdgcn_cvt_f32_fp8(u, 0), acc);
    }

    const float u = fmaxf(acc + bias[lane], 0.f);
    float s1 = u, s2 = u * u;
#pragma unroll
    for (int o = 32; o >= 1; o >>= 1) {
        s1 += __shfl_xor(s1, o);
        s2 += __shfl_xor(s2, o);
    }
    const float mu = s1 * (1.f / 64.f);
    const float var = s2 * (1.f / 64.f) - mu * mu;
    const float rs = rsqrtf(var + EPSV);
    Out[wv * 64 + lane] = (u - mu) * rs * gm[lane] + bt[lane];
}

// ---------------------------------------------------------------- pool ----
__global__ __launch_bounds__(256) void k_pool(const float* __restrict__ C,
                                              const int* __restrict__ batch,
                                              float* __restrict__ pool,
                                              int N, int chunk) {
    const int wg = blockIdx.x * 4 + (threadIdx.x >> 6);
    const int lane = threadIdx.x & 63;
    long i = (long)wg * chunk;
    const long end = (i + chunk < (long)N) ? i + chunk : (long)N;
    if (i >= end) return;

    int cur = batch[i];
    float acc = 0.f;
    int cn = 0;
    while (i < end) {
        if (i + 8 <= end && batch[i + 7] == cur) {
            float v[8];
#pragma unroll
            for (int j = 0; j < 8; ++j) v[j] = C[(i + j) * 64 + lane];
            acc += ((v[0] + v[1]) + (v[2] + v[3])) + ((v[4] + v[5]) + (v[6] + v[7]));
            cn += 8;
            i += 8;
            continue;
        }
        const int b = batch[i];
        if (b != cur) {
            unsafeAtomicAdd(&pool[cur * 64 + lane], acc);
            if (lane == 0) unsafeAtomicAdd(&pool[64 * 64 + cur], (float)cn);
            cur = b;
            acc = 0.f;
            cn = 0;
        }
        acc += C[i * 64 + lane];
        ++cn;
        ++i;
    }
    unsafeAtomicAdd(&pool[cur * 64 + lane], acc);
    if (lane == 0) unsafeAtomicAdd(&pool[64 * 64 + cur], (float)cn);
}

__global__ __launch_bounds__(256) void k_final(const float* __restrict__ pool,
                                               float* __restrict__ out) {
    const int i = blockIdx.x * 256 + threadIdx.x;
    if (i < 4096) {
        const int g = i >> 6;
        const float cnt = fmaxf(pool[64 * 64 + g], 1.0f);
        const float v = pool[i] / cnt;
        out[i] = 1.f / (1.f + expf(-v));
    }
}

// -------------------------------------------------------------- launch ----
extern "C" void kernel_launch(void* const* d_in, const int* in_sizes, int n_in,
                              void* d_out, int out_size, void* d_ws, size_t ws_size,
                              hipStream_t stream) {
    const float* x   = (const float*)d_in[0];
    const int*   ei  = (const int*)d_in[1];
    const float* ew  = (const float*)d_in[2];
    const int*   bat = (const int*)d_in[3];
    const float* W1  = (const float*)d_in[4];
    const float* b1  = (const float*)d_in[5];
    const float* g1  = (const float*)d_in[6];
    const float* bt1 = (const float*)d_in[7];
    const float* W2  = (const float*)d_in[8];
    const float* b2  = (const float*)d_in[9];
    const float* g2  = (const float*)d_in[10];
    const float* bt2 = (const float*)d_in[11];
    const int N = in_sizes[3];
    const int E = in_sizes[2];
    const int NB = (N + 255) / 256;

    u64*    dc   = (u64*)d_ws;                              // [N] packed deg/cnt
    float*  pool = (float*)(dc + N);                        // [64*64+64]
    float2* ern  = (float2*)(pool + 64 * 64 + 64);          // [E]
    unsigned char* Ah = (unsigned char*)(ern + E);          // [N*128] fp8 h1; reused h2 [N*64]
    __bf16* Bh   = (__bf16*)(Ah + (long)N * 128);           // [N*128] bf16 ln1 out
    float*  Cf   = (float*)(Bh + (long)N * 128);            // [N*64] f32 ln2 out
    float*  dinv = Cf + (long)N * 64;                       // [N]
    int*    cnt  = (int*)(dinv + N);                        // [N]
    int*    off  = cnt + N;                                 // [N]
    int*    bsum = off + N;                                 // [NB] (padded)
    unsigned short* rank = (unsigned short*)(bsum + ((NB + 3) & ~3)); // [E]
    __bf16* Wt1  = (__bf16*)(rank + E);                     // [128*256] blob
    __bf16* Wt2  = Wt1 + 128 * 256;                         // [64*128] blob

    const int nbE = (E + 255) / 256;
    const int nbW = (int)(((long)N * 64 + 255) / 256);
    const int NBM = (N + 127) / 128;

    hipMemsetAsync(dc, 0, (size_t)N * 8 + (64 * 64 + 64) * 4, stream);
    k_wcvt<<<(256 * 128 + 128 * 64 + 255) / 256, 256, 0, stream>>>(W1, Wt1, W2, Wt2);

    // fused: gemm1 (fp8 out) || degacc
    k_pre<<<NBM + nbE, 256, 0, stream>>>(x, Wt1, Ah, N, NBM, ei, ew, dc, rank, E);

    k_scanA<<<NB, 256, 0, stream>>>(dc, dinv, cnt, bsum, N);
    k_scan2<<<1, 256, 0, stream>>>(bsum, NB);
    k_scan3<<<NB, 256, 0, stream>>>(cnt, bsum, off, N);
    k_fill<<<nbE, 256, 0, stream>>>(ei, ew, dinv, off, rank, ern, E);

    // layer 1 aggregation + ReLU + LN
    k_gat128<<<nbW, 256, 0, stream>>>(Ah, off, cnt, ern, dinv, b1, g1, bt1, Bh, N);

    // layer 2: GCNConv(128->64) + ReLU + LN
    k_mm2<<<NBM, 256, 0, stream>>>(Bh, Wt2, Ah, N);
    k_gat64<<<nbW, 256, 0, stream>>>(Ah, off, cnt, ern, dinv, b2, g2, bt2, Cf, N);

    // global mean pool + sigmoid
    const int chunk = (N + 1023) / 1024;
    k_pool<<<256, 256, 0, stream>>>(Cf, bat, pool, N, chunk);
    k_final<<<16, 256, 0, stream>>>(pool, (float*)d_out);
}

// Round 8
// 314.542 us; speedup vs baseline: 16.0526x; 1.0105x over previous
//
#include <hip/hip_runtime.h>
#include <cstdint>

#define EPSV 1e-5f

typedef __bf16 bf16x8 __attribute__((ext_vector_type(8)));
typedef __bf16 bf16x2 __attribute__((ext_vector_type(2)));
typedef float  f32x4  __attribute__((ext_vector_type(4)));
typedef unsigned long long u64;

#define DEG_BLOCKS 512

// fp8 e4m3 (OCP) helpers — HW converts on gfx950.
__device__ __forceinline__ unsigned char f32_to_fp8(float x) {
    const int p = __builtin_amdgcn_cvt_pk_fp8_f32(x, x, 0, false);
    return (unsigned char)(p & 0xFF);
}

// ------------------------------- unpack: dinv + cnt + block-sum -----------
__global__ __launch_bounds__(256) void k_scanA(const u64* __restrict__ dc,
                                               float* __restrict__ dinv,
                                               int* __restrict__ cnt,
                                               int* __restrict__ bsum, int N) {
    __shared__ int ws[4];
    const int i = blockIdx.x * 256 + threadIdx.x;
    int v = 0;
    if (i < N) {
        const u64 p = dc[i];
        v = (int)(p >> 40);
        const float deg = 1.0f + (float)(p & 0xFFFFFFFFFFull) * (1.0f / 16777216.0f);
        dinv[i] = rsqrtf(deg);  // deg >= 1 always (self loop)
        cnt[i] = v;
    }
#pragma unroll
    for (int o = 32; o >= 1; o >>= 1) v += __shfl_xor(v, o);
    if ((threadIdx.x & 63) == 0) ws[threadIdx.x >> 6] = v;
    __syncthreads();
    if (threadIdx.x == 0) bsum[blockIdx.x] = ws[0] + ws[1] + ws[2] + ws[3];
}

// ---------------- merged scan: off[i] = prefix(bsum[<bid]) + local scan ---
__global__ __launch_bounds__(256) void k_scanB(const int* __restrict__ cnt,
                                               const int* __restrict__ bsum,
                                               int* __restrict__ off, int N) {
    __shared__ int pw[4];
    __shared__ int lw[4];
    __shared__ int sbase;
    const int bid = blockIdx.x;
    const int lane = threadIdx.x & 63, w = threadIdx.x >> 6;

    // block-wide sum of bsum[0..bid)
    int pre = 0;
    for (int j = threadIdx.x; j < bid; j += 256) pre += bsum[j];
#pragma unroll
    for (int o = 32; o >= 1; o >>= 1) pre += __shfl_xor(pre, o);
    if (lane == 0) pw[w] = pre;
    __syncthreads();
    if (threadIdx.x == 0) sbase = pw[0] + pw[1] + pw[2] + pw[3];

    // block-local inclusive scan of cnt
    const int i = bid * 256 + threadIdx.x;
    const int v = (i < N) ? cnt[i] : 0;
    int s = v;
#pragma unroll
    for (int o = 1; o < 64; o <<= 1) {
        const int t = __shfl_up(s, o);
        if (lane >= o) s += t;
    }
    if (lane == 63) lw[w] = s;
    __syncthreads();
    int add = sbase;
    for (int k = 0; k < w; ++k) add += lw[k];
    if (i < N) off[i] = add + s - v;
}

// ------------------- CSR fill, atomic-free: slot = off[c] + rank[e] -------
__global__ __launch_bounds__(256) void k_fill(const int* __restrict__ ei,
                                              const float* __restrict__ ew,
                                              const float* __restrict__ dinv,
                                              const int* __restrict__ off,
                                              const unsigned short* __restrict__ rank,
                                              float2* __restrict__ ern, int E) {
    const int e = blockIdx.x * 256 + threadIdx.x;
    if (e >= E) return;
    const int r = ei[e];
    const int c = ei[E + e];
    const int p = off[c] + (int)rank[e];
    ern[p] = make_float2(__int_as_float(r), dinv[r] * ew[e] * dinv[c]);
}

// ----------------------------------------------------- W transpose+cvt ----
// Blob layout: WtB[k/8][c][8] bf16, i.e. elem = ((k>>3)*NOUT + c)*8 + (k&7).
__global__ __launch_bounds__(256) void k_wcvt(const float* __restrict__ W1,
                                              __bf16* __restrict__ Wt1,
                                              const float* __restrict__ W2,
                                              __bf16* __restrict__ Wt2) {
    const int idx = blockIdx.x * 256 + threadIdx.x;
    if (idx < 256 * 128) {                       // K=256, NOUT=128
        const int k = idx >> 7, c = idx & 127;
        Wt1[(((k >> 3) << 7) + c) * 8 + (k & 7)] = (__bf16)W1[idx];
    } else if (idx < 256 * 128 + 128 * 64) {     // K=128, NOUT=64
        const int j = idx - 256 * 128;
        const int k = j >> 6, c = j & 63;
        Wt2[(((k >> 3) << 6) + c) * 8 + (k & 7)] = (__bf16)W2[j];
    }
}

// ----------------------------------------------------------- MFMA GEMM ----
// H[N][NOUT] = X[N][K] @ W -> fp8 e4m3. WtB is blob layout (see k_wcvt).
// 4 waves x 32 rows = 128-row block tile; 2 row-fragments per wave.
template <int K, int NOUT, bool ABF16>
__device__ __forceinline__ void mm_body(int bid, int tid, const void* __restrict__ Xv,
                                        const __bf16* __restrict__ WtB,
                                        unsigned char* __restrict__ H, int N) {
    constexpr int NCB = NOUT / 16;
    constexpr int NKB = K / 32;
    const int w = tid >> 6, l = tid & 63;
    const int r0 = l & 15, kq = l >> 4;
    const long tb0 = (long)bid * 128 + w * 32;
    const long ar0 = (tb0 + r0) < N ? (tb0 + r0) : (long)N - 1;
    const long ar1 = (tb0 + 16 + r0) < N ? (tb0 + 16 + r0) : (long)N - 1;

    f32x4 acc[2][NCB];
#pragma unroll
    for (int rf = 0; rf < 2; ++rf)
#pragma unroll
        for (int cb = 0; cb < NCB; ++cb) acc[rf][cb] = (f32x4){0.f, 0.f, 0.f, 0.f};

#define LDA(kb, a0, a1)                                                          \
    {                                                                            \
        const int koff = (kb) * 32 + kq * 8;                                     \
        if constexpr (ABF16) {                                                   \
            a0 = *reinterpret_cast<const bf16x8*>((const __bf16*)Xv + ar0 * K + koff); \
            a1 = *reinterpret_cast<const bf16x8*>((const __bf16*)Xv + ar1 * K + koff); \
        } else {                                                                 \
            const float* p0 = (const float*)Xv + ar0 * K + koff;                 \
            const float* p1 = (const float*)Xv + ar1 * K + koff;                 \
            const float4 u0 = *reinterpret_cast<const float4*>(p0);              \
            const float4 u1 = *reinterpret_cast<const float4*>(p0 + 4);          \
            const float4 u2 = *reinterpret_cast<const float4*>(p1);              \
            const float4 u3 = *reinterpret_cast<const float4*>(p1 + 4);          \
            a0[0] = (__bf16)u0.x; a0[1] = (__bf16)u0.y; a0[2] = (__bf16)u0.z;    \
            a0[3] = (__bf16)u0.w; a0[4] = (__bf16)u1.x; a0[5] = (__bf16)u1.y;    \
            a0[6] = (__bf16)u1.z; a0[7] = (__bf16)u1.w;                          \
            a1[0] = (__bf16)u2.x; a1[1] = (__bf16)u2.y; a1[2] = (__bf16)u2.z;    \
            a1[3] = (__bf16)u2.w; a1[4] = (__bf16)u3.x; a1[5] = (__bf16)u3.y;    \
            a1[6] = (__bf16)u3.z; a1[7] = (__bf16)u3.w;                          \
        }                                                                        \
    }

#define LDB(kb, b)                                                               \
    {                                                                            \
        const __bf16* bp = WtB + (long)(((kb) * 4 + kq) * NOUT + r0) * 8;        \
        _Pragma("unroll") for (int cb = 0; cb < NCB; ++cb)                       \
            b[cb] = *reinterpret_cast<const bf16x8*>(bp + cb * 128);             \
    }

    bf16x8 aC0, aC1, aN0, aN1;
    bf16x8 bC[NCB], bN[NCB];
    LDA(0, aC0, aC1);
    LDB(0, bC);
#pragma unroll
    for (int kb = 0; kb < NKB; ++kb) {
        if (kb + 1 < NKB) {
            LDA(kb + 1, aN0, aN1);
            LDB(kb + 1, bN);
        }
#pragma unroll
        for (int cb = 0; cb < NCB; ++cb) {
            acc[0][cb] = __builtin_amdgcn_mfma_f32_16x16x32_bf16(aC0, bC[cb], acc[0][cb], 0, 0, 0);
            acc[1][cb] = __builtin_amdgcn_mfma_f32_16x16x32_bf16(aC1, bC[cb], acc[1][cb], 0, 0, 0);
        }
        aC0 = aN0; aC1 = aN1;
#pragma unroll
        for (int cb = 0; cb < NCB; ++cb) bC[cb] = bN[cb];
    }
#undef LDA
#undef LDB

    const int orow = kq * 4;
#pragma unroll
    for (int rf = 0; rf < 2; ++rf)
#pragma unroll
        for (int cb = 0; cb < NCB; ++cb)
#pragma unroll
            for (int r = 0; r < 4; ++r) {
                const long gr = tb0 + rf * 16 + orow + r;
                if (gr < N) H[gr * NOUT + cb * 16 + r0] = f32_to_fp8(acc[rf][cb][r]);
            }
}

// -------------------- fused: degacc (512 grid-stride blocks) || gemm1 -----
// degacc blocks dispatched FIRST: few resident waves saturate the fabric's
// scattered-atomic pipe (~22 G line-RMW/s) while mm blocks use the rest of
// the machine concurrently.
__global__ __launch_bounds__(256) void k_pre(const float* __restrict__ X,
                                             const __bf16* __restrict__ Wt1,
                                             unsigned char* __restrict__ H1, int N, int NBM,
                                             const int* __restrict__ ei,
                                             const float* __restrict__ ew,
                                             u64* __restrict__ dc,
                                             unsigned short* __restrict__ rank, int E) {
    const int bid = blockIdx.x;
    if (bid < DEG_BLOCKS) {
        const int stride = DEG_BLOCKS * 256;
        for (int e = bid * 256 + threadIdx.x; e < E; e += stride) {
            const int c = ei[E + e];
            const u64 pack = (1ull << 40) | (u64)(ew[e] * 16777216.0f);
            const u64 old = atomicAdd(&dc[c], pack);
            rank[e] = (unsigned short)(old >> 40);
        }
    } else {
        mm_body<256, 128, false>(bid - DEG_BLOCKS, threadIdx.x, X, Wt1, H1, N);
    }
}

__global__ __launch_bounds__(256) void k_mm2(const __bf16* __restrict__ X,
                                             const __bf16* __restrict__ Wt2,
                                             unsigned char* __restrict__ H, int N) {
    mm_body<128, 64, true>(blockIdx.x, threadIdx.x, X, Wt2, H, N);
}

// --------------------------------- gather + bias + ReLU + LayerNorm -------
// D=128 fp8 H: one wave per node, 2 fp8 per lane; writes bf16 ln1 out.
__global__ __launch_bounds__(256) void k_gat128(const unsigned char* __restrict__ H,
                                                const int* __restrict__ off,
                                                const int* __restrict__ cnt,
                                                const float2* __restrict__ ern,
                                                const float* __restrict__ dinv,
                                                const float* __restrict__ bias,
                                                const float* __restrict__ gm,
                                                const float* __restrict__ bt,
                                                __bf16* __restrict__ Out, int N) {
    const long wv = ((long)blockIdx.x * 256 + threadIdx.x) >> 6;
    const int lane = threadIdx.x & 63;
    if (wv >= N) return;
    const int s = off[wv];
    const int n = cnt[wv];
    const float d = dinv[wv];
    const unsigned short* Hp = reinterpret_cast<const unsigned short*>(H);

    const unsigned int h0 = Hp[wv * 64 + lane];
    float ax = __builtin_amdgcn_cvt_f32_fp8(h0, 0) * d * d;
    float ay = __builtin_amdgcn_cvt_f32_fp8(h0, 1) * d * d;

    int e = 0;
    for (; e + 8 <= n; e += 8) {
        float2 q[8];
#pragma unroll
        for (int j = 0; j < 8; ++j) q[j] = ern[s + e + j];
        unsigned int u[8];
#pragma unroll
        for (int j = 0; j < 8; ++j)
            u[j] = Hp[(long)__float_as_int(q[j].x) * 64 + lane];
#pragma unroll
        for (int j = 0; j < 8; ++j) {
            ax = fmaf(q[j].y, __builtin_amdgcn_cvt_f32_fp8(u[j], 0), ax);
            ay = fmaf(q[j].y, __builtin_amdgcn_cvt_f32_fp8(u[j], 1), ay);
        }
    }
    for (; e < n; ++e) {
        const float2 q = ern[s + e];
        const unsigned int u = Hp[(long)__float_as_int(q.x) * 64 + lane];
        ax = fmaf(q.y, __builtin_amdgcn_cvt_f32_fp8(u, 0), ax);
        ay = fmaf(q.y, __builtin_amdgcn_cvt_f32_fp8(u, 1), ay);
    }

    const float ux = fmaxf(ax + bias[2 * lane], 0.f);
    const float uy = fmaxf(ay + bias[2 * lane + 1], 0.f);
    float s1 = ux + uy, s2 = ux * ux + uy * uy;
#pragma unroll
    for (int o = 32; o >= 1; o >>= 1) {
        s1 += __shfl_xor(s1, o);
        s2 += __shfl_xor(s2, o);
    }
    const float mu = s1 * (1.f / 128.f);
    const float var = s2 * (1.f / 128.f) - mu * mu;
    const float rs = rsqrtf(var + EPSV);
    bf16x2 ob;
    ob[0] = (__bf16)((ux - mu) * rs * gm[2 * lane] + bt[2 * lane]);
    ob[1] = (__bf16)((uy - mu) * rs * gm[2 * lane + 1] + bt[2 * lane + 1]);
    reinterpret_cast<bf16x2*>(Out)[wv * 64 + lane] = ob;
}

// D=64 fp8 H: one wave per node, 1 fp8 per lane; writes fp32 LN output.
__global__ __launch_bounds__(256) void k_gat64(const unsigned char* __restrict__ H,
                                               const int* __restrict__ off,
                                               const int* __restrict__ cnt,
                                               const float2* __restrict__ ern,
                                               const float* __restrict__ dinv,
                                               const float* __restrict__ bias,
                                               const float* __restrict__ gm,
                                               const float* __restrict__ bt,
                                               float* __restrict__ Out, int N) {
    const long wv = ((long)blockIdx.x * 256 + threadIdx.x) >> 6;
    const int lane = threadIdx.x & 63;
    if (wv >= N) return;
    const int s = off[wv];
    const int n = cnt[wv];
    const float d = dinv[wv];

    float acc = __builtin_amdgcn_cvt_f32_fp8((unsigned int)H[wv * 64 + lane], 0) * d * d;
    int e = 0;
    for (; e + 8 <= n; e += 8) {
        float2 q[8];
#pragma unroll
        for (int j = 0; j < 8; ++j) q[j] = ern[s + e + j];
        unsigned int u[8];
#pragma unroll
        for (int j = 0; j < 8; ++j)
            u[j] = H[(long)__float_as_int(q[j].x) * 64 + lane];
#pragma unroll
        for (int j = 0; j < 8; ++j)
            acc = fmaf(q[j].y, __builtin_amdgcn_cvt_f32_fp8(u[j], 0), acc);
    }
    for (; e < n; ++e) {
        const float2 q = ern[s + e];
        const unsigned int u = H[(long)__float_as_int(q.x) * 64 + lane];
        acc = fmaf(q.y, __builtin_amdgcn_cvt_f32_fp8(u, 0), acc);
    }

    const float u = fmaxf(acc + bias[lane], 0.f);
    float s1 = u, s2 = u * u;
#pragma unroll
    for (int o = 32; o >= 1; o >>= 1) {
        s1 += __shfl_xor(s1, o);
        s2 += __shfl_xor(s2, o);
    }
    const float mu = s1 * (1.f / 64.f);
    const float var = s2 * (1.f / 64.f) - mu * mu;
    const float rs = rsqrtf(var + EPSV);
    Out[wv * 64 + lane] = (u - mu) * rs * gm[lane] + bt[lane];
}

// ---------------------------------------------------------------- pool ----
__global__ __launch_bounds__(256) void k_pool(const float* __restrict__ C,
                                              const int* __restrict__ batch,
                                              float* __restrict__ pool,
                                              int N, int chunk) {
    const int wg = blockIdx.x * 4 + (threadIdx.x >> 6);
    const int lane = threadIdx.x & 63;
    long i = (long)wg * chunk;
    const long end = (i + chunk < (long)N) ? i + chunk : (long)N;
    if (i >= end) return;

    int cur = batch[i];
    float acc = 0.f;
    int cn = 0;
    while (i < end) {
        if (i + 8 <= end && batch[i + 7] == cur) {
            float v[8];
#pragma unroll
            for (int j = 0; j < 8; ++j) v[j] = C[(i + j) * 64 + lane];
            acc += ((v[0] + v[1]) + (v[2] + v[3])) + ((v[4] + v[5]) + (v[6] + v[7]));
            cn += 8;
            i += 8;
            continue;
        }
        const int b = batch[i];
        if (b != cur) {
            unsafeAtomicAdd(&pool[cur * 64 + lane], acc);
            if (lane == 0) unsafeAtomicAdd(&pool[64 * 64 + cur], (float)cn);
            cur = b;
            acc = 0.f;
            cn = 0;
        }
        acc += C[i * 64 + lane];
        ++cn;
        ++i;
    }
    unsafeAtomicAdd(&pool[cur * 64 + lane], acc);
    if (lane == 0) unsafeAtomicAdd(&pool[64 * 64 + cur], (float)cn);
}

__global__ __launch_bounds__(256) void k_final(const float* __restrict__ pool,
                                               float* __restrict__ out) {
    const int i = blockIdx.x * 256 + threadIdx.x;
    if (i < 4096) {
        const int g = i >> 6;
        const float cnt = fmaxf(pool[64 * 64 + g], 1.0f);
        const float v = pool[i] / cnt;
        out[i] = 1.f / (1.f + expf(-v));
    }
}

// -------------------------------------------------------------- launch ----
extern "C" void kernel_launch(void* const* d_in, const int* in_sizes, int n_in,
                              void* d_out, int out_size, void* d_ws, size_t ws_size,
                              hipStream_t stream) {
    const float* x   = (const float*)d_in[0];
    const int*   ei  = (const int*)d_in[1];
    const float* ew  = (const float*)d_in[2];
    const int*   bat = (const int*)d_in[3];
    const float* W1  = (const float*)d_in[4];
    const float* b1  = (const float*)d_in[5];
    const float* g1  = (const float*)d_in[6];
    const float* bt1 = (const float*)d_in[7];
    const float* W2  = (const float*)d_in[8];
    const float* b2  = (const float*)d_in[9];
    const float* g2  = (const float*)d_in[10];
    const float* bt2 = (const float*)d_in[11];
    const int N = in_sizes[3];
    const int E = in_sizes[2];
    const int NB = (N + 255) / 256;

    u64*    dc   = (u64*)d_ws;                              // [N] packed deg/cnt
    float*  pool = (float*)(dc + N);                        // [64*64+64]
    float2* ern  = (float2*)(pool + 64 * 64 + 64);          // [E]
    unsigned char* Ah = (unsigned char*)(ern + E);          // [N*128] fp8 h1; reused h2 [N*64]
    __bf16* Bh   = (__bf16*)(Ah + (long)N * 128);           // [N*128] bf16 ln1 out
    float*  Cf   = (float*)(Bh + (long)N * 128);            // [N*64] f32 ln2 out
    float*  dinv = Cf + (long)N * 64;                       // [N]
    int*    cnt  = (int*)(dinv + N);                        // [N]
    int*    off  = cnt + N;                                 // [N]
    int*    bsum = off + N;                                 // [NB] (padded)
    unsigned short* rank = (unsigned short*)(bsum + ((NB + 3) & ~3)); // [E]
    __bf16* Wt1  = (__bf16*)(rank + E);                     // [128*256] blob
    __bf16* Wt2  = Wt1 + 128 * 256;                         // [64*128] blob

    const int nbE = (E + 255) / 256;
    const int nbW = (int)(((long)N * 64 + 255) / 256);
    const int NBM = (N + 127) / 128;

    hipMemsetAsync(dc, 0, (size_t)N * 8 + (64 * 64 + 64) * 4, stream);
    k_wcvt<<<(256 * 128 + 128 * 64 + 255) / 256, 256, 0, stream>>>(W1, Wt1, W2, Wt2);

    // fused: degacc (512 grid-stride blocks, first) || gemm1 (fp8 out)
    k_pre<<<DEG_BLOCKS + NBM, 256, 0, stream>>>(x, Wt1, Ah, N, NBM, ei, ew, dc, rank, E);

    k_scanA<<<NB, 256, 0, stream>>>(dc, dinv, cnt, bsum, N);
    k_scanB<<<NB, 256, 0, stream>>>(cnt, bsum, off, N);
    k_fill<<<nbE, 256, 0, stream>>>(ei, ew, dinv, off, rank, ern, E);

    // layer 1 aggregation + ReLU + LN
    k_gat128<<<nbW, 256, 0, stream>>>(Ah, off, cnt, ern, dinv, b1, g1, bt1, Bh, N);

    // layer 2: GCNConv(128->64) + ReLU + LN
    k_mm2<<<NBM, 256, 0, stream>>>(Bh, Wt2, Ah, N);
    k_gat64<<<nbW, 256, 0, stream>>>(Ah, off, cnt, ern, dinv, b2, g2, bt2, Cf, N);

    // global mean pool + sigmoid
    const int chunk = (N + 1023) / 1024;
    k_pool<<<256, 256, 0, stream>>>(Cf, bat, pool, N, chunk);
    k_final<<<16, 256, 0, stream>>>(pool, (float*)d_out);
}